// Round 7
// baseline (264.760 us; speedup 1.0000x reference)
//
#include <hip/hip_runtime.h>

typedef unsigned short u16;
typedef unsigned int u32;
typedef __attribute__((ext_vector_type(8))) short short8;    // 8 bf16
typedef __attribute__((ext_vector_type(16))) float f32x16;

#define BB 8
#define NN 4096
#define NPP 1024
#define NSS 32
#define CFF 64
#define C0 67
#define H0 64
#define H1 128
#define H2 256
#define NTOT (BB*NN)        // 32768 points
#define MTOT (BB*NPP*NSS)   // 262144
#define BN_EPS 1e-5f
#define INV_M (1.0f/262144.0f)

#define MFMA32(a,b,c) __builtin_amdgcn_mfma_f32_32x32x16_bf16(a,b,c,0,0,0)

__device__ __forceinline__ float bf2f(u16 h){ return __uint_as_float(((u32)h)<<16); }
__device__ __forceinline__ u16 f2bf(float f){
  u32 u = __float_as_uint(f);
  u32 r = (u + 0x7fffu + ((u>>16)&1u)) >> 16;
  return (u16)r;
}
__device__ __forceinline__ u32 pack2(float a, float b){
  return (u32)f2bf(a) | ((u32)f2bf(b)<<16);
}

// ---------------------------------------------------------------------------
// R7: conv0 factorized per-point: y0[m] = U[nb(m)] - T[sp(p(m))], exact algebra.
// U[n] = W0f·feat[n] + W0xyz·xyz[n]; T[n] = W0xyz·xyz[n]. N=32768 (8x < M).
// U,T are 4.2 MB bf16 each -> L2-resident; y0 (67 MB HBM traffic) deleted.
// Chunked-K layout [k/8][row][8 bf16]; 32x32x16 MFMA; C/D: col=lane&31,
// row=(r&3)+8*(r>>2)+4*(lane>>5).
//
// ws layout (bytes), total 16,918,528:
//   stats [0,49152) 3x4096 f32 | Wt0c [49152,59392) [10][64][8]
//   Wt1c [59392,75776) [8][128][8] | Wt2c [75776,141312) [16][256][8]
//   U [141312,4335616) (NTOT,64) bf16 | T [4335616,8529920)
//   mxp [8529920,12724224) | mnp [12724224,16918528)
// ---------------------------------------------------------------------------
#define WS_NEED 16918528u

// ---------------------------------------------------------------------------
// Setup: new_xyz copy + weight packing. Grid 42.
// W0 chunk order: kc 0..7 = feat ch (W0 col 3+k), kc 8 = xyz (cols 0..2 + pad),
// kc 9 = zeros.
// ---------------------------------------------------------------------------
__global__ __launch_bounds__(256) void k_setup(
    const float* __restrict__ xyz, const int* __restrict__ sidx,
    const float* __restrict__ W0, const float* __restrict__ W1, const float* __restrict__ W2,
    u16* __restrict__ Wt0c, u16* __restrict__ Wt1c, u16* __restrict__ Wt2c,
    float* __restrict__ out_newxyz)
{
  int blk = blockIdx.x, tid = threadIdx.x;
  if (blk < 32) {
    int t0 = blk*256 + tid;                  // b*NP + p
    int b = t0 >> 10;
    int s = sidx[t0];
    for (int k = 0; k < 3; ++k)
      out_newxyz[(size_t)t0*3 + k] = xyz[((size_t)(b*NN + s))*3 + k];
  } else if (blk == 32) {
    for (int i = 0; i < 20; ++i) {
      int e = i*256 + tid;                   // [10 kc][64 o][8 j]
      if (e >= 5120) break;
      int kc = e >> 9, o = (e >> 3) & 63, j = e & 7;
      float v;
      if (kc < 8)       v = W0[o*C0 + 3 + kc*8 + j];
      else if (kc == 8) v = (j < 3) ? W0[o*C0 + j] : 0.f;
      else              v = 0.f;
      Wt0c[e] = f2bf(v);
    }
  } else if (blk == 33) {
    for (int i = 0; i < 32; ++i) {
      int e = i*256 + tid;                   // [8 kc][128 n][8 j]
      int kc = e >> 10, n = (e >> 3) & 127, j = e & 7;
      Wt1c[e] = f2bf(W1[n*H0 + kc*8 + j]);
    }
  } else {
    int base = (blk - 34) * 4096;            // blocks 34..41
    for (int i = 0; i < 16; ++i) {
      int e = base + i*256 + tid;            // [16 kc][256 n][8 j]
      int kc = e >> 11, n = (e >> 3) & 255, j = e & 7;
      Wt2c[e] = f2bf(W2[n*H1 + kc*8 + j]);
    }
  }
}

__global__ __launch_bounds__(256) void k_xyz_only(
    const float* __restrict__ xyz, const int* __restrict__ sidx, float* __restrict__ out_newxyz)
{
  int t0 = blockIdx.x*256 + threadIdx.x;
  int b = t0 >> 10;
  int s = sidx[t0];
  for (int k = 0; k < 3; ++k)
    out_newxyz[(size_t)t0*3 + k] = xyz[((size_t)(b*NN + s))*3 + k];
}

// ---------------------------------------------------------------------------
// UV: per-point GEMM. M=128 points/block, grid 256. K=80 (10 chunks):
// accT from chunks 8,9 (xyz), accU = accT + chunks 0..7 (feat).
// ---------------------------------------------------------------------------
__global__ __launch_bounds__(256) void k_uv(
    const float* __restrict__ xyz, const float* __restrict__ points,
    const u16* __restrict__ Wt0c, u16* __restrict__ U, u16* __restrict__ T)
{
  __shared__ u16 XLc[10*128*8];  // 20 KB
  __shared__ u16 W0c[10*64*8];   // 10 KB
  int tid = threadIdx.x;
  int gn0 = blockIdx.x * 128;
  int b = gn0 >> 12;
  int n0 = gn0 & 4095;

  for (int i = 0; i < 3; ++i) {
    int e = i*256 + tid;
    if (e < 640) ((uint4*)W0c)[e] = ((const uint4*)Wt0c)[e];
  }
  {
    int c = tid >> 2, nseg = tid & 3;        // 64 ch x 4 n-segments
    const float* src = points + ((size_t)(b*CFF + c))*NN + n0 + nseg*32;
    int cb = c >> 3, cr = c & 7;
    for (int t = 0; t < 8; ++t) {
      float4 v = *(const float4*)(src + t*4);
      int n = nseg*32 + t*4;
      XLc[(cb*128 + n+0)*8 + cr] = f2bf(v.x);
      XLc[(cb*128 + n+1)*8 + cr] = f2bf(v.y);
      XLc[(cb*128 + n+2)*8 + cr] = f2bf(v.z);
      XLc[(cb*128 + n+3)*8 + cr] = f2bf(v.w);
    }
  }
  if (tid < 128) {
    int gn = gn0 + tid;
    float x = xyz[(size_t)gn*3+0], y = xyz[(size_t)gn*3+1], z = xyz[(size_t)gn*3+2];
    uint4 v = { pack2(x,y), pack2(z,0.f), 0u, 0u };
    *(uint4*)&XLc[(8*128 + tid)*8] = v;
  } else {
    uint4 z4 = {0u,0u,0u,0u};
    *(uint4*)&XLc[(9*128 + (tid-128))*8] = z4;
  }
  __syncthreads();

  int lane = tid & 63, wv = tid >> 6, l31 = lane & 31, kh = lane >> 5;
  int nt = wv & 1, mtb = (wv >> 1)*2;
  f32x16 accT2[2], accU2[2];
  for (int mi = 0; mi < 2; ++mi) for (int r = 0; r < 16; ++r) accT2[mi][r] = 0.f;

  {
    int ck = 8 + kh;
    short8 bfrag = *(const short8*)&W0c[(ck*64 + nt*32 + l31)*8];
    for (int mi = 0; mi < 2; ++mi) {
      short8 afrag = *(const short8*)&XLc[(ck*128 + (mtb+mi)*32 + l31)*8];
      accT2[mi] = MFMA32(afrag, bfrag, accT2[mi]);
    }
  }
  for (int mi = 0; mi < 2; ++mi) accU2[mi] = accT2[mi];
  for (int kt = 0; kt < 4; ++kt) {
    int ck = kt*2 + kh;
    short8 bfrag = *(const short8*)&W0c[(ck*64 + nt*32 + l31)*8];
    for (int mi = 0; mi < 2; ++mi) {
      short8 afrag = *(const short8*)&XLc[(ck*128 + (mtb+mi)*32 + l31)*8];
      accU2[mi] = MFMA32(afrag, bfrag, accU2[mi]);
    }
  }

  int c = nt*32 + l31;
  for (int mi = 0; mi < 2; ++mi)
    for (int r = 0; r < 16; ++r) {
      int gm = gn0 + (mtb+mi)*32 + (r&3) + 8*(r>>2) + 4*kh;
      U[(size_t)gm*64 + c] = f2bf(accU2[mi][r]);
      T[(size_t)gm*64 + c] = f2bf(accT2[mi][r]);
    }
}

// ---------------------------------------------------------------------------
// stats0: gather U - T over M, per-channel sum/sumsq. Grid 2048, 128 m/block.
// thread: 4 channels (c0=(tid&15)*4), 8 rows (rg=tid>>4).
// ---------------------------------------------------------------------------
__global__ __launch_bounds__(256) void k_s0(
    const int* __restrict__ sidx, const int* __restrict__ nidx,
    const u16* __restrict__ U, const u16* __restrict__ T, float* __restrict__ stats)
{
  int tid = threadIdx.x;
  int m0 = blockIdx.x * 128;
  int b = m0 >> 15;
  int c0 = (tid & 15) * 4;
  int rg = tid >> 4;
  int mbase = m0 + rg*8;
  int p = (mbase & 32767) >> 5;
  int sp = sidx[b*NPP + p];
  u16 tv[4];
  *(uint2*)tv = *(const uint2*)(T + ((size_t)(b*NN + sp))*64 + c0);
  float t0 = bf2f(tv[0]), t1 = bf2f(tv[1]), t2 = bf2f(tv[2]), t3 = bf2f(tv[3]);
  float s0=0.f,s1=0.f,s2=0.f,s3=0.f,q0=0.f,q1=0.f,q2=0.f,q3=0.f;
  for (int i = 0; i < 8; ++i) {
    int nb = nidx[mbase + i];
    u16 uv[4];
    *(uint2*)uv = *(const uint2*)(U + ((size_t)(b*NN + nb))*64 + c0);
    float d0 = bf2f(uv[0]) - t0; s0 += d0; q0 += d0*d0;
    float d1 = bf2f(uv[1]) - t1; s1 += d1; q1 += d1*d1;
    float d2 = bf2f(uv[2]) - t2; s2 += d2; q2 += d2*d2;
    float d3 = bf2f(uv[3]) - t3; s3 += d3; q3 += d3*d3;
  }
  for (int msk = 16; msk <= 32; msk <<= 1) {
    s0 += __shfl_xor(s0, msk); s1 += __shfl_xor(s1, msk);
    s2 += __shfl_xor(s2, msk); s3 += __shfl_xor(s3, msk);
    q0 += __shfl_xor(q0, msk); q1 += __shfl_xor(q1, msk);
    q2 += __shfl_xor(q2, msk); q3 += __shfl_xor(q3, msk);
  }
  if ((tid & 63) < 16) {
    int slot = (blockIdx.x*4 + (tid >> 6)) & 7;
    atomicAdd(&stats[slot*256 + c0+0], s0);
    atomicAdd(&stats[slot*256 + c0+1], s1);
    atomicAdd(&stats[slot*256 + c0+2], s2);
    atomicAdd(&stats[slot*256 + c0+3], s3);
    atomicAdd(&stats[2048 + slot*256 + c0+0], q0);
    atomicAdd(&stats[2048 + slot*256 + c0+1], q1);
    atomicAdd(&stats[2048 + slot*256 + c0+2], q2);
    atomicAdd(&stats[2048 + slot*256 + c0+3], q3);
  }
}

// ---------------------------------------------------------------------------
// L1 stats: gather U-T, BN0+ReLU -> X0c, GEMM1 -> stats1. M=128, grid 2048.
// ---------------------------------------------------------------------------
__global__ __launch_bounds__(256) void k_l1s(
    const int* __restrict__ sidx, const int* __restrict__ nidx,
    const u16* __restrict__ U, const u16* __restrict__ T, const u16* __restrict__ Wt1c,
    const float* __restrict__ g0, const float* __restrict__ e0,
    const float* __restrict__ stIn, float* __restrict__ stOut)
{
  __shared__ u16 X0c[8*128*8];   // 16 KB
  __shared__ u16 W1c[8*128*8];   // 16 KB
  __shared__ float scl0[64], sft0[64];
  int tid = threadIdx.x;
  int m0 = blockIdx.x * 128;
  int b = m0 >> 15;

  if (tid < 64) {
    float s = 0.f, q = 0.f;
    for (int sl = 0; sl < 8; ++sl) { s += stIn[sl*256 + tid]; q += stIn[2048 + sl*256 + tid]; }
    float mu = s*INV_M, var = q*INV_M - mu*mu;
    float sc = g0[tid] * rsqrtf(var + BN_EPS);
    scl0[tid] = sc; sft0[tid] = e0[tid] - mu*sc;
  }
  for (int i = 0; i < 4; ++i)
    ((uint4*)W1c)[i*256 + tid] = ((const uint4*)Wt1c)[i*256 + tid];

  int pos = tid & 127, half = tid >> 7;
  {
    int m = m0 + pos;
    int nb = nidx[m];
    int p = (m & 32767) >> 5;
    int sp = sidx[b*NPP + p];
    const u16* urow = U + ((size_t)(b*NN + nb))*64 + half*32;
    const u16* trow = T + ((size_t)(b*NN + sp))*64 + half*32;
    u16 us[32], ts[32];
    for (int t = 0; t < 4; ++t) {
      *(uint4*)&us[t*8] = ((const uint4*)urow)[t];
      *(uint4*)&ts[t*8] = ((const uint4*)trow)[t];
    }
    __syncthreads();   // scl0 ready
    u16 ob[32];
    for (int j = 0; j < 32; ++j) {
      int c = half*32 + j;
      float d = bf2f(us[j]) - bf2f(ts[j]);
      ob[j] = f2bf(fmaxf(fmaf(scl0[c], d, sft0[c]), 0.f));
    }
    for (int t = 0; t < 4; ++t)
      *(uint4*)&X0c[((half*4+t)*128 + pos)*8] = *(uint4*)&ob[t*8];
  }
  __syncthreads();

  int lane = tid & 63, wv = tid >> 6, l31 = lane & 31, kh = lane >> 5;
  f32x16 acc[4];
  for (int mt = 0; mt < 4; ++mt) for (int r = 0; r < 16; ++r) acc[mt][r] = 0.f;

  for (int kt = 0; kt < 4; ++kt) {
    int ck = kt*2 + kh;
    short8 bfrag = *(const short8*)&W1c[(ck*128 + wv*32 + l31)*8];
    for (int mt = 0; mt < 4; ++mt) {
      short8 afrag = *(const short8*)&X0c[(ck*128 + mt*32 + l31)*8];
      acc[mt] = MFMA32(afrag, bfrag, acc[mt]);
    }
  }

  float s = 0.f, q = 0.f;
  for (int mt = 0; mt < 4; ++mt)
    for (int r = 0; r < 16; ++r) { float y = acc[mt][r]; s += y; q += y*y; }
  s += __shfl_xor(s, 32); q += __shfl_xor(q, 32);
  if (lane < 32) {
    int slot = blockIdx.x & 7;
    atomicAdd(&stOut[slot*256 + wv*32 + lane], s);
    atomicAdd(&stOut[2048 + slot*256 + wv*32 + lane], q);
  }
}

// ---------------------------------------------------------------------------
// L2 fused: gather U-T -> BN0+ReLU -> GEMM1 (A=W1,B=X0: C rows=ch!) -> BN1+ReLU
// -> b64 scatter into padded X1c -> GEMM2 -> stats2 + max/min. M=64, grid 4096.
// ---------------------------------------------------------------------------
__global__ __launch_bounds__(256) void k_l2f(
    const int* __restrict__ sidx, const int* __restrict__ nidx,
    const u16* __restrict__ U, const u16* __restrict__ T,
    const u16* __restrict__ Wt1c, const u16* __restrict__ Wt2c,
    const float* __restrict__ g0, const float* __restrict__ e0,
    const float* __restrict__ g1, const float* __restrict__ e1,
    const float* __restrict__ st0, const float* __restrict__ st1, float* __restrict__ stOut,
    u16* __restrict__ mxp, u16* __restrict__ mnp)
{
  __shared__ u16 X1c[16*520];    // 16.3 KB, padded chunks (stride 520 u16)
  __shared__ u16 UB[16384];      // 32 KB: ph1 X0c[0,4096)+W1c[4096,12288); ph2 W2 half
  __shared__ float scl0[64], sft0[64], scl1[128], sft1[128];
  int tid = threadIdx.x;
  int m0 = blockIdx.x * 64;
  int b = m0 >> 15;

  if (tid < 64) {
    float s = 0.f, q = 0.f;
    for (int sl = 0; sl < 8; ++sl) { s += st0[sl*256 + tid]; q += st0[2048 + sl*256 + tid]; }
    float mu = s*INV_M, var = q*INV_M - mu*mu;
    float sc = g0[tid] * rsqrtf(var + BN_EPS);
    scl0[tid] = sc; sft0[tid] = e0[tid] - mu*sc;
  }
  if (tid < 128) {
    float s = 0.f, q = 0.f;
    for (int sl = 0; sl < 8; ++sl) { s += st1[sl*256 + tid]; q += st1[2048 + sl*256 + tid]; }
    float mu = s*INV_M, var = q*INV_M - mu*mu;
    float sc = g1[tid] * rsqrtf(var + BN_EPS);
    scl1[tid] = sc; sft1[tid] = e1[tid] - mu*sc;
  }
  u16* X0c = UB;          // [8 kc][64 m][8]
  u16* W1c = UB + 4096;   // [8 kc][128 n][8]
  for (int i = 0; i < 4; ++i)
    ((uint4*)W1c)[i*256 + tid] = ((const uint4*)Wt1c)[i*256 + tid];

  int pos = tid & 63, grp = tid >> 6;
  {
    int m = m0 + pos;
    int nb = nidx[m];
    int p = (m & 32767) >> 5;
    int sp = sidx[b*NPP + p];
    const u16* urow = U + ((size_t)(b*NN + nb))*64 + grp*16;
    const u16* trow = T + ((size_t)(b*NN + sp))*64 + grp*16;
    u16 us[16], ts[16];
    *(uint4*)&us[0] = ((const uint4*)urow)[0];
    *(uint4*)&us[8] = ((const uint4*)urow)[1];
    *(uint4*)&ts[0] = ((const uint4*)trow)[0];
    *(uint4*)&ts[8] = ((const uint4*)trow)[1];
    __syncthreads();   // scl0/scl1 ready, W1c staged
    u16 ob[16];
    for (int j = 0; j < 16; ++j) {
      int c = grp*16 + j;
      float d = bf2f(us[j]) - bf2f(ts[j]);
      ob[j] = f2bf(fmaxf(fmaf(scl0[c], d, sft0[c]), 0.f));
    }
    *(uint4*)&X0c[((2*grp)*64 + pos)*8]   = *(uint4*)&ob[0];
    *(uint4*)&X0c[((2*grp+1)*64 + pos)*8] = *(uint4*)&ob[8];
  }
  __syncthreads();

  int lane = tid & 63, wv = tid >> 6, l31 = lane & 31, kh = lane >> 5;

  // ---- GEMM1 swapped: A=W1 (rows=ch, wave's 32-ch tile = wv), B=X0 (cols=pos) ----
  f32x16 acc1[2];
  for (int nt = 0; nt < 2; ++nt) for (int r = 0; r < 16; ++r) acc1[nt][r] = 0.f;
  for (int kt = 0; kt < 4; ++kt) {
    int ck = kt*2 + kh;
    short8 afrag = *(const short8*)&W1c[(ck*128 + wv*32 + l31)*8];
    for (int nt = 0; nt < 2; ++nt) {
      short8 bfrag = *(const short8*)&X0c[(ck*64 + nt*32 + l31)*8];
      acc1[nt] = MFMA32(afrag, bfrag, acc1[nt]);
    }
  }
  __syncthreads();   // all UB (X0c/W1c) reads done

  // ---- BN1+ReLU + b64 scatter (4 consecutive channels per write) ----
  {
    float s1r[16], f1r[16];
    for (int r = 0; r < 16; ++r) {
      int ch = wv*32 + (r&3) + 8*(r>>2) + 4*kh;
      s1r[r] = scl1[ch]; f1r[r] = sft1[ch];
    }
    for (int nt = 0; nt < 2; ++nt) {
      int posn = nt*32 + l31;
      for (int g = 0; g < 4; ++g) {
        float v0 = fmaxf(fmaf(s1r[g*4+0], acc1[nt][g*4+0], f1r[g*4+0]), 0.f);
        float v1 = fmaxf(fmaf(s1r[g*4+1], acc1[nt][g*4+1], f1r[g*4+1]), 0.f);
        float v2 = fmaxf(fmaf(s1r[g*4+2], acc1[nt][g*4+2], f1r[g*4+2]), 0.f);
        float v3 = fmaxf(fmaf(s1r[g*4+3], acc1[nt][g*4+3], f1r[g*4+3]), 0.f);
        uint2 w = { pack2(v0, v1), pack2(v2, v3) };
        *(uint2*)&X1c[(wv*4 + g)*520 + posn*8 + 4*kh] = w;
      }
    }
  }
  __syncthreads();   // X1c complete before GEMM2 / UB overwrite

  // ---- GEMM2: A=X1 (rows=pos), B=W2 (cols=ch); W2 staged in 32KB halves ----
  f32x16 acc2[2][2];
  for (int nt = 0; nt < 2; ++nt) for (int mt = 0; mt < 2; ++mt)
    for (int r = 0; r < 16; ++r) acc2[nt][mt][r] = 0.f;

  for (int h = 0; h < 2; ++h) {
    for (int i = 0; i < 8; ++i)
      ((uint4*)UB)[i*256 + tid] = ((const uint4*)Wt2c)[h*2048 + i*256 + tid];
    __syncthreads();
    for (int k4 = 0; k4 < 4; ++k4) {
      int ckx = (h*4 + k4)*2 + kh;
      int ckw = k4*2 + kh;
      short8 a[2], bf_[2];
      for (int mt = 0; mt < 2; ++mt) a[mt]  = *(const short8*)&X1c[ckx*520 + (mt*32 + l31)*8];
      for (int nt = 0; nt < 2; ++nt) bf_[nt] = *(const short8*)&UB[(ckw*256 + wv*64 + nt*32 + l31)*8];
      for (int nt = 0; nt < 2; ++nt)
        for (int mt = 0; mt < 2; ++mt)
          acc2[nt][mt] = MFMA32(a[mt], bf_[nt], acc2[nt][mt]);
    }
    __syncthreads();
  }

  // ---- stats2 + max/min over NS (p-groups = row tiles mt) ----
  int slot = blockIdx.x & 7;
  for (int nt = 0; nt < 2; ++nt) {
    float s = 0.f, q = 0.f;
    float mx[2] = {-3.0e38f, -3.0e38f}, mn[2] = {3.0e38f, 3.0e38f};
    for (int mt = 0; mt < 2; ++mt)
      for (int r = 0; r < 16; ++r) {
        float y = acc2[nt][mt][r];
        s += y; q += y*y;
        mx[mt] = fmaxf(mx[mt], y); mn[mt] = fminf(mn[mt], y);
      }
    s += __shfl_xor(s, 32); q += __shfl_xor(q, 32);
    mx[0] = fmaxf(mx[0], __shfl_xor(mx[0], 32));
    mx[1] = fmaxf(mx[1], __shfl_xor(mx[1], 32));
    mn[0] = fminf(mn[0], __shfl_xor(mn[0], 32));
    mn[1] = fminf(mn[1], __shfl_xor(mn[1], 32));
    if (lane < 32) {
      int c = wv*64 + nt*32 + lane;
      atomicAdd(&stOut[slot*256 + c], s);
      atomicAdd(&stOut[2048 + slot*256 + c], q);
      for (int mt = 0; mt < 2; ++mt) {
        size_t pr = (size_t)blockIdx.x*2 + mt;
        mxp[pr*H2 + c] = f2bf(mx[mt]);
        mnp[pr*H2 + c] = f2bf(mn[mt]);
      }
    }
  }
}

// ---------------------------------------------------------------------------
__global__ __launch_bounds__(256) void k_final(
    const u16* __restrict__ mxp, const u16* __restrict__ mnp,
    const float* __restrict__ gma, const float* __restrict__ bta,
    const float* __restrict__ stIn, float* __restrict__ out_np)
{
  __shared__ float tmp[256][33];
  int tid = threadIdx.x;
  int b = blockIdx.x >> 5;
  int p0 = (blockIdx.x & 31) * 32;

  float s = 0.f, q = 0.f;
  for (int sl = 0; sl < 8; ++sl) { s += stIn[sl*256 + tid]; q += stIn[2048 + sl*256 + tid]; }
  float mu = s*INV_M, var = q*INV_M - mu*mu;
  float sc = gma[tid] * rsqrtf(var + BN_EPS);
  float sh = bta[tid] - mu*sc;

  for (int pp = 0; pp < 32; ++pp) {
    size_t base = ((size_t)(b*NPP + p0 + pp))*H2 + tid;
    float xv = bf2f(mxp[base]), nv = bf2f(mnp[base]);
    float v = (sc >= 0.f) ? fmaf(sc, xv, sh) : fmaf(sc, nv, sh);
    tmp[tid][pp] = fmaxf(v, 0.f);
  }
  __syncthreads();

  int pl = tid & 31, cg = tid >> 5;
  for (int cc = 0; cc < 32; ++cc) {
    int c = cc*8 + cg;
    out_np[((size_t)b*H2 + c)*NPP + p0 + pl] = tmp[c][pl];
  }
}

// ---------------------------------------------------------------------------
extern "C" void kernel_launch(void* const* d_in, const int* in_sizes, int n_in,
                              void* d_out, int out_size, void* d_ws, size_t ws_size,
                              hipStream_t stream)
{
  const float* xyz    = (const float*)d_in[0];
  const float* points = (const float*)d_in[1];
  const int*   sidx   = (const int*)d_in[2];
  const int*   nidx   = (const int*)d_in[3];
  const float* W0 = (const float*)d_in[4];
  const float* g0 = (const float*)d_in[6];
  const float* e0 = (const float*)d_in[7];
  const float* W1 = (const float*)d_in[8];
  const float* g1 = (const float*)d_in[10];
  const float* e1 = (const float*)d_in[11];
  const float* W2 = (const float*)d_in[12];
  const float* g2 = (const float*)d_in[14];
  const float* e2 = (const float*)d_in[15];

  float* out_xyz = (float*)d_out;
  float* out_np  = out_xyz + (size_t)BB*NPP*3;

  if (ws_size < (size_t)WS_NEED) {
    hipMemsetAsync(out_np, 0, (size_t)BB*H2*NPP*4, stream);
    k_xyz_only<<<32, 256, 0, stream>>>(xyz, sidx, out_xyz);
    return;
  }

  char* ws = (char*)d_ws;
  float* stats = (float*)(ws + 0);
  u16*   Wt0c  = (u16*)(ws + 49152);
  u16*   Wt1c  = (u16*)(ws + 59392);
  u16*   Wt2c  = (u16*)(ws + 75776);
  u16*   Ubuf  = (u16*)(ws + 141312);
  u16*   Tbuf  = (u16*)(ws + 4335616);
  u16*   mxp   = (u16*)(ws + 8529920);
  u16*   mnp   = (u16*)(ws + 12724224);

  hipMemsetAsync(stats, 0, 3*4096*sizeof(float), stream);
  k_setup<<<42, 256, 0, stream>>>(xyz, sidx, W0, W1, W2, Wt0c, Wt1c, Wt2c, out_xyz);
  k_uv<<<NTOT/128, 256, 0, stream>>>(xyz, points, Wt0c, Ubuf, Tbuf);
  k_s0<<<MTOT/128, 256, 0, stream>>>(sidx, nidx, Ubuf, Tbuf, stats);
  k_l1s<<<MTOT/128, 256, 0, stream>>>(sidx, nidx, Ubuf, Tbuf, Wt1c, g0, e0,
                                      stats, stats + 4096);
  k_l2f<<<MTOT/64, 256, 0, stream>>>(sidx, nidx, Ubuf, Tbuf, Wt1c, Wt2c,
                                     g0, e0, g1, e1,
                                     stats, stats + 4096, stats + 8192, mxp, mnp);
  k_final<<<256, 256, 0, stream>>>(mxp, mnp, g2, e2, stats + 8192, out_np);
}

// Round 8
// 225.854 us; speedup vs baseline: 1.1723x; 1.1723x over previous
//
#include <hip/hip_runtime.h>

typedef unsigned short u16;
typedef unsigned int u32;
typedef __attribute__((ext_vector_type(8))) short short8;    // 8 bf16
typedef __attribute__((ext_vector_type(16))) float f32x16;

#define BB 8
#define NN 4096
#define NPP 1024
#define NSS 32
#define CFF 64
#define C0 67
#define H0 64
#define H1 128
#define H2 256
#define NTOT (BB*NN)        // 32768 points
#define MTOT (BB*NPP*NSS)   // 262144
#define BN_EPS 1e-5f
#define INV_M (1.0f/262144.0f)
#define NSLOT 64
#define SQOFF 16384         // 64 slots * 256 ch
#define LSTRIDE 32768       // floats per layer (sum + sq)

#define MFMA32(a,b,c) __builtin_amdgcn_mfma_f32_32x32x16_bf16(a,b,c,0,0,0)

__device__ __forceinline__ float bf2f(u16 h){ return __uint_as_float(((u32)h)<<16); }
__device__ __forceinline__ u16 f2bf(float f){
  u32 u = __float_as_uint(f);
  u32 r = (u + 0x7fffu + ((u>>16)&1u)) >> 16;
  return (u16)r;
}
__device__ __forceinline__ u32 pack2(float a, float b){
  return (u32)f2bf(a) | ((u32)f2bf(b)<<16);
}

// ---------------------------------------------------------------------------
// R8: same structure as R7 (U/T conv0 factorization), atomics fixed.
// HW law (R7 post-mortem): global float atomics write through (~16B/atomic in
// WRITE_SIZE) and same-address chains serialize at ~100cyc/op. Keep
// ops-per-address <= ~256: 64 stat slots, slot = (blockIdx*4+wave)&63.
//
// ws layout (bytes), total 17,262,592:
//   stats [0,393216)           3 layers x [64 slots][256] sum + [64][256] sq, f32
//   Wt0c  [393216,403456)      [10][64][8] bf16
//   Wt1c  [403456,419840)      [8][128][8]
//   Wt2c  [419840,485376)      [16][256][8]
//   U     [485376,4679680)     (NTOT,64) bf16
//   T     [4679680,8873984)
//   mxp   [8873984,13068288)   (B*NP,256) bf16
//   mnp   [13068288,17262592)
// ---------------------------------------------------------------------------
#define WS_NEED 17262592u

__global__ __launch_bounds__(256) void k_setup(
    const float* __restrict__ xyz, const int* __restrict__ sidx,
    const float* __restrict__ W0, const float* __restrict__ W1, const float* __restrict__ W2,
    u16* __restrict__ Wt0c, u16* __restrict__ Wt1c, u16* __restrict__ Wt2c,
    float* __restrict__ out_newxyz)
{
  int blk = blockIdx.x, tid = threadIdx.x;
  if (blk < 32) {
    int t0 = blk*256 + tid;                  // b*NP + p
    int b = t0 >> 10;
    int s = sidx[t0];
    for (int k = 0; k < 3; ++k)
      out_newxyz[(size_t)t0*3 + k] = xyz[((size_t)(b*NN + s))*3 + k];
  } else if (blk == 32) {
    for (int i = 0; i < 20; ++i) {
      int e = i*256 + tid;                   // [10 kc][64 o][8 j]
      if (e >= 5120) break;
      int kc = e >> 9, o = (e >> 3) & 63, j = e & 7;
      float v;
      if (kc < 8)       v = W0[o*C0 + 3 + kc*8 + j];
      else if (kc == 8) v = (j < 3) ? W0[o*C0 + j] : 0.f;
      else              v = 0.f;
      Wt0c[e] = f2bf(v);
    }
  } else if (blk == 33) {
    for (int i = 0; i < 32; ++i) {
      int e = i*256 + tid;                   // [8 kc][128 n][8 j]
      int kc = e >> 10, n = (e >> 3) & 127, j = e & 7;
      Wt1c[e] = f2bf(W1[n*H0 + kc*8 + j]);
    }
  } else {
    int base = (blk - 34) * 4096;            // blocks 34..41
    for (int i = 0; i < 16; ++i) {
      int e = base + i*256 + tid;            // [16 kc][256 n][8 j]
      int kc = e >> 11, n = (e >> 3) & 255, j = e & 7;
      Wt2c[e] = f2bf(W2[n*H1 + kc*8 + j]);
    }
  }
}

__global__ __launch_bounds__(256) void k_xyz_only(
    const float* __restrict__ xyz, const int* __restrict__ sidx, float* __restrict__ out_newxyz)
{
  int t0 = blockIdx.x*256 + threadIdx.x;
  int b = t0 >> 10;
  int s = sidx[t0];
  for (int k = 0; k < 3; ++k)
    out_newxyz[(size_t)t0*3 + k] = xyz[((size_t)(b*NN + s))*3 + k];
}

// ---------------------------------------------------------------------------
// UV: per-point GEMM. M=128 points/block, grid 256. K=80 (10 chunks):
// accT from chunks 8,9 (xyz), accU = accT + chunks 0..7 (feat).
// ---------------------------------------------------------------------------
__global__ __launch_bounds__(256) void k_uv(
    const float* __restrict__ xyz, const float* __restrict__ points,
    const u16* __restrict__ Wt0c, u16* __restrict__ U, u16* __restrict__ T)
{
  __shared__ u16 XLc[10*128*8];  // 20 KB
  __shared__ u16 W0c[10*64*8];   // 10 KB
  int tid = threadIdx.x;
  int gn0 = blockIdx.x * 128;
  int b = gn0 >> 12;
  int n0 = gn0 & 4095;

  for (int i = 0; i < 3; ++i) {
    int e = i*256 + tid;
    if (e < 640) ((uint4*)W0c)[e] = ((const uint4*)Wt0c)[e];
  }
  {
    int c = tid >> 2, nseg = tid & 3;        // 64 ch x 4 n-segments
    const float* src = points + ((size_t)(b*CFF + c))*NN + n0 + nseg*32;
    int cb = c >> 3, cr = c & 7;
    for (int t = 0; t < 8; ++t) {
      float4 v = *(const float4*)(src + t*4);
      int n = nseg*32 + t*4;
      XLc[(cb*128 + n+0)*8 + cr] = f2bf(v.x);
      XLc[(cb*128 + n+1)*8 + cr] = f2bf(v.y);
      XLc[(cb*128 + n+2)*8 + cr] = f2bf(v.z);
      XLc[(cb*128 + n+3)*8 + cr] = f2bf(v.w);
    }
  }
  if (tid < 128) {
    int gn = gn0 + tid;
    float x = xyz[(size_t)gn*3+0], y = xyz[(size_t)gn*3+1], z = xyz[(size_t)gn*3+2];
    uint4 v = { pack2(x,y), pack2(z,0.f), 0u, 0u };
    *(uint4*)&XLc[(8*128 + tid)*8] = v;
  } else {
    uint4 z4 = {0u,0u,0u,0u};
    *(uint4*)&XLc[(9*128 + (tid-128))*8] = z4;
  }
  __syncthreads();

  int lane = tid & 63, wv = tid >> 6, l31 = lane & 31, kh = lane >> 5;
  int nt = wv & 1, mtb = (wv >> 1)*2;
  f32x16 accT2[2], accU2[2];
  for (int mi = 0; mi < 2; ++mi) for (int r = 0; r < 16; ++r) accT2[mi][r] = 0.f;

  {
    int ck = 8 + kh;
    short8 bfrag = *(const short8*)&W0c[(ck*64 + nt*32 + l31)*8];
    for (int mi = 0; mi < 2; ++mi) {
      short8 afrag = *(const short8*)&XLc[(ck*128 + (mtb+mi)*32 + l31)*8];
      accT2[mi] = MFMA32(afrag, bfrag, accT2[mi]);
    }
  }
  for (int mi = 0; mi < 2; ++mi) accU2[mi] = accT2[mi];
  for (int kt = 0; kt < 4; ++kt) {
    int ck = kt*2 + kh;
    short8 bfrag = *(const short8*)&W0c[(ck*64 + nt*32 + l31)*8];
    for (int mi = 0; mi < 2; ++mi) {
      short8 afrag = *(const short8*)&XLc[(ck*128 + (mtb+mi)*32 + l31)*8];
      accU2[mi] = MFMA32(afrag, bfrag, accU2[mi]);
    }
  }

  int c = nt*32 + l31;
  for (int mi = 0; mi < 2; ++mi)
    for (int r = 0; r < 16; ++r) {
      int gm = gn0 + (mtb+mi)*32 + (r&3) + 8*(r>>2) + 4*kh;
      U[(size_t)gm*64 + c] = f2bf(accU2[mi][r]);
      T[(size_t)gm*64 + c] = f2bf(accT2[mi][r]);
    }
}

// ---------------------------------------------------------------------------
// stats0: gather U-T, per-channel sum/sumsq. Grid 2048, 128 m/block.
// thread: 8 ch (uint4 loads), 4 m. Wave = 1 p (T row wave-uniform).
// shfl-reduce rg (bits 3..5) -> lanes<8 emit; 64 slots.
// ---------------------------------------------------------------------------
__global__ __launch_bounds__(256) void k_s0(
    const int* __restrict__ sidx, const int* __restrict__ nidx,
    const u16* __restrict__ U, const u16* __restrict__ T, float* __restrict__ stats)
{
  int tid = threadIdx.x;
  int m0 = blockIdx.x * 128;
  int b = m0 >> 15;
  int c0 = (tid & 7) * 8;
  int rg = tid >> 3;              // 0..31, wave wv covers rg [wv*8, wv*8+8)
  int wv = tid >> 6;
  int mbase = m0 + rg*4;
  int p = (mbase & 32767) >> 5;
  int sp = sidx[b*NPP + p];
  u16 tv[8];
  *(uint4*)tv = *(const uint4*)(T + ((size_t)(b*NN + sp))*64 + c0);
  float tf[8], s[8], q[8];
  for (int j = 0; j < 8; ++j) { tf[j] = bf2f(tv[j]); s[j] = 0.f; q[j] = 0.f; }
  for (int i = 0; i < 4; ++i) {
    int nb = nidx[mbase + i];
    u16 uv[8];
    *(uint4*)uv = *(const uint4*)(U + ((size_t)(b*NN + nb))*64 + c0);
    for (int j = 0; j < 8; ++j) {
      float d = bf2f(uv[j]) - tf[j];
      s[j] += d; q[j] += d*d;
    }
  }
  for (int msk = 8; msk <= 32; msk <<= 1)
    for (int j = 0; j < 8; ++j) {
      s[j] += __shfl_xor(s[j], msk);
      q[j] += __shfl_xor(q[j], msk);
    }
  if ((tid & 63) < 8) {
    int slot = (blockIdx.x*4 + wv) & 63;
    for (int j = 0; j < 8; ++j) {
      atomicAdd(&stats[slot*256 + c0 + j], s[j]);
      atomicAdd(&stats[SQOFF + slot*256 + c0 + j], q[j]);
    }
  }
}

// ---------------------------------------------------------------------------
// L1 stats: gather U-T, BN0+ReLU -> X0c, GEMM1 -> stats1. M=128, grid 2048.
// ---------------------------------------------------------------------------
__global__ __launch_bounds__(256) void k_l1s(
    const int* __restrict__ sidx, const int* __restrict__ nidx,
    const u16* __restrict__ U, const u16* __restrict__ T, const u16* __restrict__ Wt1c,
    const float* __restrict__ g0, const float* __restrict__ e0,
    const float* __restrict__ stIn, float* __restrict__ stOut)
{
  __shared__ u16 X0c[8*128*8];   // 16 KB
  __shared__ u16 W1c[8*128*8];   // 16 KB
  __shared__ float scl0[64], sft0[64];
  int tid = threadIdx.x;
  int m0 = blockIdx.x * 128;
  int b = m0 >> 15;

  if (tid < 64) {
    float s = 0.f, q = 0.f;
    for (int sl = 0; sl < NSLOT; ++sl) { s += stIn[sl*256 + tid]; q += stIn[SQOFF + sl*256 + tid]; }
    float mu = s*INV_M, var = q*INV_M - mu*mu;
    float sc = g0[tid] * rsqrtf(var + BN_EPS);
    scl0[tid] = sc; sft0[tid] = e0[tid] - mu*sc;
  }
  for (int i = 0; i < 4; ++i)
    ((uint4*)W1c)[i*256 + tid] = ((const uint4*)Wt1c)[i*256 + tid];

  int pos = tid & 127, half = tid >> 7;
  {
    int m = m0 + pos;
    int nb = nidx[m];
    int p = (m & 32767) >> 5;
    int sp = sidx[b*NPP + p];
    const u16* urow = U + ((size_t)(b*NN + nb))*64 + half*32;
    const u16* trow = T + ((size_t)(b*NN + sp))*64 + half*32;
    u16 us[32], ts[32];
    for (int t = 0; t < 4; ++t) {
      *(uint4*)&us[t*8] = ((const uint4*)urow)[t];
      *(uint4*)&ts[t*8] = ((const uint4*)trow)[t];
    }
    __syncthreads();   // scl0 ready
    u16 ob[32];
    for (int j = 0; j < 32; ++j) {
      int c = half*32 + j;
      float d = bf2f(us[j]) - bf2f(ts[j]);
      ob[j] = f2bf(fmaxf(fmaf(scl0[c], d, sft0[c]), 0.f));
    }
    for (int t = 0; t < 4; ++t)
      *(uint4*)&X0c[((half*4+t)*128 + pos)*8] = *(uint4*)&ob[t*8];
  }
  __syncthreads();

  int lane = tid & 63, wv = tid >> 6, l31 = lane & 31, kh = lane >> 5;
  f32x16 acc[4];
  for (int mt = 0; mt < 4; ++mt) for (int r = 0; r < 16; ++r) acc[mt][r] = 0.f;

  for (int kt = 0; kt < 4; ++kt) {
    int ck = kt*2 + kh;
    short8 bfrag = *(const short8*)&W1c[(ck*128 + wv*32 + l31)*8];
    for (int mt = 0; mt < 4; ++mt) {
      short8 afrag = *(const short8*)&X0c[(ck*128 + mt*32 + l31)*8];
      acc[mt] = MFMA32(afrag, bfrag, acc[mt]);
    }
  }

  float s = 0.f, q = 0.f;
  for (int mt = 0; mt < 4; ++mt)
    for (int r = 0; r < 16; ++r) { float y = acc[mt][r]; s += y; q += y*y; }
  s += __shfl_xor(s, 32); q += __shfl_xor(q, 32);
  if (lane < 32) {
    int slot = (blockIdx.x*4 + wv) & 63;
    atomicAdd(&stOut[slot*256 + wv*32 + lane], s);
    atomicAdd(&stOut[SQOFF + slot*256 + wv*32 + lane], q);
  }
}

// ---------------------------------------------------------------------------
// L2 fused: gather U-T -> BN0+ReLU -> GEMM1 (A=W1,B=X0) -> BN1+ReLU -> b64
// scatter into padded X1c -> GEMM2 -> stats2 + max/min. M=64, grid 4096.
// ---------------------------------------------------------------------------
__global__ __launch_bounds__(256) void k_l2f(
    const int* __restrict__ sidx, const int* __restrict__ nidx,
    const u16* __restrict__ U, const u16* __restrict__ T,
    const u16* __restrict__ Wt1c, const u16* __restrict__ Wt2c,
    const float* __restrict__ g0, const float* __restrict__ e0,
    const float* __restrict__ g1, const float* __restrict__ e1,
    const float* __restrict__ st0, const float* __restrict__ st1, float* __restrict__ stOut,
    u16* __restrict__ mxp, u16* __restrict__ mnp)
{
  __shared__ u16 X1c[16*520];    // padded chunks (stride 520 u16)
  __shared__ u16 UB[16384];      // 32 KB: ph1 X0c[0,4096)+W1c[4096,12288); ph2 W2 half
  __shared__ float scl0[64], sft0[64], scl1[128], sft1[128];
  int tid = threadIdx.x;
  int m0 = blockIdx.x * 64;
  int b = m0 >> 15;

  if (tid < 64) {
    float s = 0.f, q = 0.f;
    for (int sl = 0; sl < NSLOT; ++sl) { s += st0[sl*256 + tid]; q += st0[SQOFF + sl*256 + tid]; }
    float mu = s*INV_M, var = q*INV_M - mu*mu;
    float sc = g0[tid] * rsqrtf(var + BN_EPS);
    scl0[tid] = sc; sft0[tid] = e0[tid] - mu*sc;
  }
  if (tid < 128) {
    float s = 0.f, q = 0.f;
    for (int sl = 0; sl < NSLOT; ++sl) { s += st1[sl*256 + tid]; q += st1[SQOFF + sl*256 + tid]; }
    float mu = s*INV_M, var = q*INV_M - mu*mu;
    float sc = g1[tid] * rsqrtf(var + BN_EPS);
    scl1[tid] = sc; sft1[tid] = e1[tid] - mu*sc;
  }
  u16* X0c = UB;          // [8 kc][64 m][8]
  u16* W1c = UB + 4096;   // [8 kc][128 n][8]
  for (int i = 0; i < 4; ++i)
    ((uint4*)W1c)[i*256 + tid] = ((const uint4*)Wt1c)[i*256 + tid];

  int pos = tid & 63, grp = tid >> 6;
  {
    int m = m0 + pos;
    int nb = nidx[m];
    int p = (m & 32767) >> 5;
    int sp = sidx[b*NPP + p];
    const u16* urow = U + ((size_t)(b*NN + nb))*64 + grp*16;
    const u16* trow = T + ((size_t)(b*NN + sp))*64 + grp*16;
    u16 us[16], ts[16];
    *(uint4*)&us[0] = ((const uint4*)urow)[0];
    *(uint4*)&us[8] = ((const uint4*)urow)[1];
    *(uint4*)&ts[0] = ((const uint4*)trow)[0];
    *(uint4*)&ts[8] = ((const uint4*)trow)[1];
    __syncthreads();   // scl0/scl1 ready, W1c staged
    u16 ob[16];
    for (int j = 0; j < 16; ++j) {
      int c = grp*16 + j;
      float d = bf2f(us[j]) - bf2f(ts[j]);
      ob[j] = f2bf(fmaxf(fmaf(scl0[c], d, sft0[c]), 0.f));
    }
    *(uint4*)&X0c[((2*grp)*64 + pos)*8]   = *(uint4*)&ob[0];
    *(uint4*)&X0c[((2*grp+1)*64 + pos)*8] = *(uint4*)&ob[8];
  }
  __syncthreads();

  int lane = tid & 63, wv = tid >> 6, l31 = lane & 31, kh = lane >> 5;

  // ---- GEMM1 swapped: A=W1 (rows=ch, wave's 32-ch tile = wv), B=X0 (cols=pos) ----
  f32x16 acc1[2];
  for (int nt = 0; nt < 2; ++nt) for (int r = 0; r < 16; ++r) acc1[nt][r] = 0.f;
  for (int kt = 0; kt < 4; ++kt) {
    int ck = kt*2 + kh;
    short8 afrag = *(const short8*)&W1c[(ck*128 + wv*32 + l31)*8];
    for (int nt = 0; nt < 2; ++nt) {
      short8 bfrag = *(const short8*)&X0c[(ck*64 + nt*32 + l31)*8];
      acc1[nt] = MFMA32(afrag, bfrag, acc1[nt]);
    }
  }
  __syncthreads();   // all UB (X0c/W1c) reads done

  // ---- BN1+ReLU + b64 scatter (4 consecutive channels per write) ----
  {
    float s1r[16], f1r[16];
    for (int r = 0; r < 16; ++r) {
      int ch = wv*32 + (r&3) + 8*(r>>2) + 4*kh;
      s1r[r] = scl1[ch]; f1r[r] = sft1[ch];
    }
    for (int nt = 0; nt < 2; ++nt) {
      int posn = nt*32 + l31;
      for (int g = 0; g < 4; ++g) {
        float v0 = fmaxf(fmaf(s1r[g*4+0], acc1[nt][g*4+0], f1r[g*4+0]), 0.f);
        float v1 = fmaxf(fmaf(s1r[g*4+1], acc1[nt][g*4+1], f1r[g*4+1]), 0.f);
        float v2 = fmaxf(fmaf(s1r[g*4+2], acc1[nt][g*4+2], f1r[g*4+2]), 0.f);
        float v3 = fmaxf(fmaf(s1r[g*4+3], acc1[nt][g*4+3], f1r[g*4+3]), 0.f);
        uint2 w = { pack2(v0, v1), pack2(v2, v3) };
        *(uint2*)&X1c[(wv*4 + g)*520 + posn*8 + 4*kh] = w;
      }
    }
  }
  __syncthreads();   // X1c complete before GEMM2 / UB overwrite

  // ---- GEMM2: A=X1 (rows=pos), B=W2 (cols=ch); W2 staged in 32KB halves ----
  f32x16 acc2[2][2];
  for (int nt = 0; nt < 2; ++nt) for (int mt = 0; mt < 2; ++mt)
    for (int r = 0; r < 16; ++r) acc2[nt][mt][r] = 0.f;

  for (int h = 0; h < 2; ++h) {
    for (int i = 0; i < 8; ++i)
      ((uint4*)UB)[i*256 + tid] = ((const uint4*)Wt2c)[h*2048 + i*256 + tid];
    __syncthreads();
    for (int k4 = 0; k4 < 4; ++k4) {
      int ckx = (h*4 + k4)*2 + kh;
      int ckw = k4*2 + kh;
      short8 a[2], bf_[2];
      for (int mt = 0; mt < 2; ++mt) a[mt]  = *(const short8*)&X1c[ckx*520 + (mt*32 + l31)*8];
      for (int nt = 0; nt < 2; ++nt) bf_[nt] = *(const short8*)&UB[(ckw*256 + wv*64 + nt*32 + l31)*8];
      for (int nt = 0; nt < 2; ++nt)
        for (int mt = 0; mt < 2; ++mt)
          acc2[nt][mt] = MFMA32(a[mt], bf_[nt], acc2[nt][mt]);
    }
    __syncthreads();
  }

  // ---- stats2 + max/min over NS (p-groups = row tiles mt) ----
  int slot = (blockIdx.x*4 + wv) & 63;
  for (int nt = 0; nt < 2; ++nt) {
    float s = 0.f, q = 0.f;
    float mx[2] = {-3.0e38f, -3.0e38f}, mn[2] = {3.0e38f, 3.0e38f};
    for (int mt = 0; mt < 2; ++mt)
      for (int r = 0; r < 16; ++r) {
        float y = acc2[nt][mt][r];
        s += y; q += y*y;
        mx[mt] = fmaxf(mx[mt], y); mn[mt] = fminf(mn[mt], y);
      }
    s += __shfl_xor(s, 32); q += __shfl_xor(q, 32);
    mx[0] = fmaxf(mx[0], __shfl_xor(mx[0], 32));
    mx[1] = fmaxf(mx[1], __shfl_xor(mx[1], 32));
    mn[0] = fminf(mn[0], __shfl_xor(mn[0], 32));
    mn[1] = fminf(mn[1], __shfl_xor(mn[1], 32));
    if (lane < 32) {
      int c = wv*64 + nt*32 + lane;
      atomicAdd(&stOut[slot*256 + c], s);
      atomicAdd(&stOut[SQOFF + slot*256 + c], q);
      for (int mt = 0; mt < 2; ++mt) {
        size_t pr = (size_t)blockIdx.x*2 + mt;
        mxp[pr*H2 + c] = f2bf(mx[mt]);
        mnp[pr*H2 + c] = f2bf(mn[mt]);
      }
    }
  }
}

// ---------------------------------------------------------------------------
__global__ __launch_bounds__(256) void k_final(
    const u16* __restrict__ mxp, const u16* __restrict__ mnp,
    const float* __restrict__ gma, const float* __restrict__ bta,
    const float* __restrict__ stIn, float* __restrict__ out_np)
{
  __shared__ float tmp[256][33];
  int tid = threadIdx.x;
  int b = blockIdx.x >> 5;
  int p0 = (blockIdx.x & 31) * 32;

  float s = 0.f, q = 0.f;
  for (int sl = 0; sl < NSLOT; ++sl) { s += stIn[sl*256 + tid]; q += stIn[SQOFF + sl*256 + tid]; }
  float mu = s*INV_M, var = q*INV_M - mu*mu;
  float sc = gma[tid] * rsqrtf(var + BN_EPS);
  float sh = bta[tid] - mu*sc;

  for (int pp = 0; pp < 32; ++pp) {
    size_t base = ((size_t)(b*NPP + p0 + pp))*H2 + tid;
    float xv = bf2f(mxp[base]), nv = bf2f(mnp[base]);
    float v = (sc >= 0.f) ? fmaf(sc, xv, sh) : fmaf(sc, nv, sh);
    tmp[tid][pp] = fmaxf(v, 0.f);
  }
  __syncthreads();

  int pl = tid & 31, cg = tid >> 5;
  for (int cc = 0; cc < 32; ++cc) {
    int c = cc*8 + cg;
    out_np[((size_t)b*H2 + c)*NPP + p0 + pl] = tmp[c][pl];
  }
}

// ---------------------------------------------------------------------------
extern "C" void kernel_launch(void* const* d_in, const int* in_sizes, int n_in,
                              void* d_out, int out_size, void* d_ws, size_t ws_size,
                              hipStream_t stream)
{
  const float* xyz    = (const float*)d_in[0];
  const float* points = (const float*)d_in[1];
  const int*   sidx   = (const int*)d_in[2];
  const int*   nidx   = (const int*)d_in[3];
  const float* W0 = (const float*)d_in[4];
  const float* g0 = (const float*)d_in[6];
  const float* e0 = (const float*)d_in[7];
  const float* W1 = (const float*)d_in[8];
  const float* g1 = (const float*)d_in[10];
  const float* e1 = (const float*)d_in[11];
  const float* W2 = (const float*)d_in[12];
  const float* g2 = (const float*)d_in[14];
  const float* e2 = (const float*)d_in[15];

  float* out_xyz = (float*)d_out;
  float* out_np  = out_xyz + (size_t)BB*NPP*3;

  if (ws_size < (size_t)WS_NEED) {
    hipMemsetAsync(out_np, 0, (size_t)BB*H2*NPP*4, stream);
    k_xyz_only<<<32, 256, 0, stream>>>(xyz, sidx, out_xyz);
    return;
  }

  char* ws = (char*)d_ws;
  float* stats = (float*)(ws + 0);
  u16*   Wt0c  = (u16*)(ws + 393216);
  u16*   Wt1c  = (u16*)(ws + 403456);
  u16*   Wt2c  = (u16*)(ws + 419840);
  u16*   Ubuf  = (u16*)(ws + 485376);
  u16*   Tbuf  = (u16*)(ws + 4679680);
  u16*   mxp   = (u16*)(ws + 8873984);
  u16*   mnp   = (u16*)(ws + 13068288);

  hipMemsetAsync(stats, 0, 3*LSTRIDE*sizeof(float), stream);
  k_setup<<<42, 256, 0, stream>>>(xyz, sidx, W0, W1, W2, Wt0c, Wt1c, Wt2c, out_xyz);
  k_uv<<<NTOT/128, 256, 0, stream>>>(xyz, points, Wt0c, Ubuf, Tbuf);
  k_s0<<<MTOT/128, 256, 0, stream>>>(sidx, nidx, Ubuf, Tbuf, stats);
  k_l1s<<<MTOT/128, 256, 0, stream>>>(sidx, nidx, Ubuf, Tbuf, Wt1c, g0, e0,
                                      stats, stats + LSTRIDE);
  k_l2f<<<MTOT/64, 256, 0, stream>>>(sidx, nidx, Ubuf, Tbuf, Wt1c, Wt2c,
                                     g0, e0, g1, e1,
                                     stats, stats + LSTRIDE, stats + 2*LSTRIDE, mxp, mnp);
  k_final<<<256, 256, 0, stream>>>(mxp, mnp, g2, e2, stats + 2*LSTRIDE, out_np);
}

// Round 9
// 213.605 us; speedup vs baseline: 1.2395x; 1.0573x over previous
//
#include <hip/hip_runtime.h>

typedef unsigned short u16;
typedef unsigned int u32;
typedef __attribute__((ext_vector_type(8))) short short8;    // 8 bf16
typedef __attribute__((ext_vector_type(16))) float f32x16;

#define BB 8
#define NN 4096
#define NPP 1024
#define NSS 32
#define CFF 64
#define C0 67
#define H0 64
#define H1 128
#define H2 256
#define NTOT (BB*NN)        // 32768 points
#define MTOT (BB*NPP*NSS)   // 262144
#define BN_EPS 1e-5f
#define INV_M (1.0f/262144.0f)
#define NSLOT 64
#define SQOFF 16384         // 64 slots * 256 ch
#define LSTRIDE 32768       // floats per layer (sum + sq)

#define MFMA32(a,b,c) __builtin_amdgcn_mfma_f32_32x32x16_bf16(a,b,c,0,0,0)

__device__ __forceinline__ float bf2f(u16 h){ return __uint_as_float(((u32)h)<<16); }
__device__ __forceinline__ u16 f2bf(float f){
  u32 u = __float_as_uint(f);
  u32 r = (u + 0x7fffu + ((u>>16)&1u)) >> 16;
  return (u16)r;
}
__device__ __forceinline__ u32 pack2(float a, float b){
  return (u32)f2bf(a) | ((u32)f2bf(b)<<16);
}

// ---------------------------------------------------------------------------
// R9: R8 structure + BN-constant finalization hoisted into k_fin (grid=1)
// kernels. Consumers load scl/sft with ONE coalesced load instead of running
// a 64-slot strided reduction per block (R8's l2f stall).
//
// ws layout (bytes), total 17,268,736:
//   stats [0,393216)           3 layers x [64][256] sum + [64][256] sq f32
//   Wt0c  [393216,403456)      [10][64][8] bf16
//   Wt1c  [403456,419840)      [8][128][8]
//   Wt2c  [419840,485376)      [16][256][8]
//   U     [485376,4679680)     (NTOT,64) bf16
//   T     [4679680,8873984)
//   mxp   [8873984,13068288)   (B*NP,256) bf16
//   mnp   [13068288,17262592)
//   bnc   [17262592,17268736)  6 x 256 f32: scl0,sft0,scl1,sft1,scl2,sft2
// ---------------------------------------------------------------------------
#define WS_NEED 17268736u

__global__ __launch_bounds__(256) void k_setup(
    const float* __restrict__ xyz, const int* __restrict__ sidx,
    const float* __restrict__ W0, const float* __restrict__ W1, const float* __restrict__ W2,
    u16* __restrict__ Wt0c, u16* __restrict__ Wt1c, u16* __restrict__ Wt2c,
    float* __restrict__ out_newxyz)
{
  int blk = blockIdx.x, tid = threadIdx.x;
  if (blk < 32) {
    int t0 = blk*256 + tid;                  // b*NP + p
    int b = t0 >> 10;
    int s = sidx[t0];
    for (int k = 0; k < 3; ++k)
      out_newxyz[(size_t)t0*3 + k] = xyz[((size_t)(b*NN + s))*3 + k];
  } else if (blk == 32) {
    for (int i = 0; i < 20; ++i) {
      int e = i*256 + tid;                   // [10 kc][64 o][8 j]
      if (e >= 5120) break;
      int kc = e >> 9, o = (e >> 3) & 63, j = e & 7;
      float v;
      if (kc < 8)       v = W0[o*C0 + 3 + kc*8 + j];
      else if (kc == 8) v = (j < 3) ? W0[o*C0 + j] : 0.f;
      else              v = 0.f;
      Wt0c[e] = f2bf(v);
    }
  } else if (blk == 33) {
    for (int i = 0; i < 32; ++i) {
      int e = i*256 + tid;                   // [8 kc][128 n][8 j]
      int kc = e >> 10, n = (e >> 3) & 127, j = e & 7;
      Wt1c[e] = f2bf(W1[n*H0 + kc*8 + j]);
    }
  } else {
    int base = (blk - 34) * 4096;            // blocks 34..41
    for (int i = 0; i < 16; ++i) {
      int e = base + i*256 + tid;            // [16 kc][256 n][8 j]
      int kc = e >> 11, n = (e >> 3) & 255, j = e & 7;
      Wt2c[e] = f2bf(W2[n*H1 + kc*8 + j]);
    }
  }
}

__global__ __launch_bounds__(256) void k_xyz_only(
    const float* __restrict__ xyz, const int* __restrict__ sidx, float* __restrict__ out_newxyz)
{
  int t0 = blockIdx.x*256 + threadIdx.x;
  int b = t0 >> 10;
  int s = sidx[t0];
  for (int k = 0; k < 3; ++k)
    out_newxyz[(size_t)t0*3 + k] = xyz[((size_t)(b*NN + s))*3 + k];
}

// ---------------------------------------------------------------------------
// fin: reduce 64 stat slots -> scl/sft (grid = 1 block)
// ---------------------------------------------------------------------------
__global__ __launch_bounds__(256) void k_fin(
    const float* __restrict__ stIn, const float* __restrict__ gma,
    const float* __restrict__ bta, int nch,
    float* __restrict__ sclG, float* __restrict__ sftG)
{
  int c = threadIdx.x;
  if (c < nch) {
    float s = 0.f, q = 0.f;
    for (int sl = 0; sl < NSLOT; ++sl) { s += stIn[sl*256 + c]; q += stIn[SQOFF + sl*256 + c]; }
    float mu = s*INV_M, var = q*INV_M - mu*mu;
    float sc = gma[c] * rsqrtf(var + BN_EPS);
    sclG[c] = sc; sftG[c] = bta[c] - mu*sc;
  }
}

// ---------------------------------------------------------------------------
// UV: per-point GEMM. M=128 points/block, grid 256. K=80 (10 chunks):
// accT from chunks 8,9 (xyz), accU = accT + chunks 0..7 (feat).
// ---------------------------------------------------------------------------
__global__ __launch_bounds__(256) void k_uv(
    const float* __restrict__ xyz, const float* __restrict__ points,
    const u16* __restrict__ Wt0c, u16* __restrict__ U, u16* __restrict__ T)
{
  __shared__ u16 XLc[10*128*8];  // 20 KB
  __shared__ u16 W0c[10*64*8];   // 10 KB
  int tid = threadIdx.x;
  int gn0 = blockIdx.x * 128;
  int b = gn0 >> 12;
  int n0 = gn0 & 4095;

  for (int i = 0; i < 3; ++i) {
    int e = i*256 + tid;
    if (e < 640) ((uint4*)W0c)[e] = ((const uint4*)Wt0c)[e];
  }
  {
    int c = tid >> 2, nseg = tid & 3;        // 64 ch x 4 n-segments
    const float* src = points + ((size_t)(b*CFF + c))*NN + n0 + nseg*32;
    int cb = c >> 3, cr = c & 7;
    for (int t = 0; t < 8; ++t) {
      float4 v = *(const float4*)(src + t*4);
      int n = nseg*32 + t*4;
      XLc[(cb*128 + n+0)*8 + cr] = f2bf(v.x);
      XLc[(cb*128 + n+1)*8 + cr] = f2bf(v.y);
      XLc[(cb*128 + n+2)*8 + cr] = f2bf(v.z);
      XLc[(cb*128 + n+3)*8 + cr] = f2bf(v.w);
    }
  }
  if (tid < 128) {
    int gn = gn0 + tid;
    float x = xyz[(size_t)gn*3+0], y = xyz[(size_t)gn*3+1], z = xyz[(size_t)gn*3+2];
    uint4 v = { pack2(x,y), pack2(z,0.f), 0u, 0u };
    *(uint4*)&XLc[(8*128 + tid)*8] = v;
  } else {
    uint4 z4 = {0u,0u,0u,0u};
    *(uint4*)&XLc[(9*128 + (tid-128))*8] = z4;
  }
  __syncthreads();

  int lane = tid & 63, wv = tid >> 6, l31 = lane & 31, kh = lane >> 5;
  int nt = wv & 1, mtb = (wv >> 1)*2;
  f32x16 accT2[2], accU2[2];
  for (int mi = 0; mi < 2; ++mi) for (int r = 0; r < 16; ++r) accT2[mi][r] = 0.f;

  {
    int ck = 8 + kh;
    short8 bfrag = *(const short8*)&W0c[(ck*64 + nt*32 + l31)*8];
    for (int mi = 0; mi < 2; ++mi) {
      short8 afrag = *(const short8*)&XLc[(ck*128 + (mtb+mi)*32 + l31)*8];
      accT2[mi] = MFMA32(afrag, bfrag, accT2[mi]);
    }
  }
  for (int mi = 0; mi < 2; ++mi) accU2[mi] = accT2[mi];
  for (int kt = 0; kt < 4; ++kt) {
    int ck = kt*2 + kh;
    short8 bfrag = *(const short8*)&W0c[(ck*64 + nt*32 + l31)*8];
    for (int mi = 0; mi < 2; ++mi) {
      short8 afrag = *(const short8*)&XLc[(ck*128 + (mtb+mi)*32 + l31)*8];
      accU2[mi] = MFMA32(afrag, bfrag, accU2[mi]);
    }
  }

  int c = nt*32 + l31;
  for (int mi = 0; mi < 2; ++mi)
    for (int r = 0; r < 16; ++r) {
      int gm = gn0 + (mtb+mi)*32 + (r&3) + 8*(r>>2) + 4*kh;
      U[(size_t)gm*64 + c] = f2bf(accU2[mi][r]);
      T[(size_t)gm*64 + c] = f2bf(accT2[mi][r]);
    }
}

// ---------------------------------------------------------------------------
// stats0: gather U-T, per-channel sum/sumsq. Grid 2048, 128 m/block.
// ---------------------------------------------------------------------------
__global__ __launch_bounds__(256) void k_s0(
    const int* __restrict__ sidx, const int* __restrict__ nidx,
    const u16* __restrict__ U, const u16* __restrict__ T, float* __restrict__ stats)
{
  int tid = threadIdx.x;
  int m0 = blockIdx.x * 128;
  int b = m0 >> 15;
  int c0 = (tid & 7) * 8;
  int rg = tid >> 3;
  int wv = tid >> 6;
  int mbase = m0 + rg*4;
  int p = (mbase & 32767) >> 5;
  int sp = sidx[b*NPP + p];
  u16 tv[8];
  *(uint4*)tv = *(const uint4*)(T + ((size_t)(b*NN + sp))*64 + c0);
  float tf[8], s[8], q[8];
  for (int j = 0; j < 8; ++j) { tf[j] = bf2f(tv[j]); s[j] = 0.f; q[j] = 0.f; }
  for (int i = 0; i < 4; ++i) {
    int nb = nidx[mbase + i];
    u16 uv[8];
    *(uint4*)uv = *(const uint4*)(U + ((size_t)(b*NN + nb))*64 + c0);
    for (int j = 0; j < 8; ++j) {
      float d = bf2f(uv[j]) - tf[j];
      s[j] += d; q[j] += d*d;
    }
  }
  for (int msk = 8; msk <= 32; msk <<= 1)
    for (int j = 0; j < 8; ++j) {
      s[j] += __shfl_xor(s[j], msk);
      q[j] += __shfl_xor(q[j], msk);
    }
  if ((tid & 63) < 8) {
    int slot = (blockIdx.x*4 + wv) & 63;
    for (int j = 0; j < 8; ++j) {
      atomicAdd(&stats[slot*256 + c0 + j], s[j]);
      atomicAdd(&stats[SQOFF + slot*256 + c0 + j], q[j]);
    }
  }
}

// ---------------------------------------------------------------------------
// L1 stats: gather U-T, BN0+ReLU -> X0c, GEMM1 -> stats1. M=128, grid 2048.
// ---------------------------------------------------------------------------
__global__ __launch_bounds__(256) void k_l1s(
    const int* __restrict__ sidx, const int* __restrict__ nidx,
    const u16* __restrict__ U, const u16* __restrict__ T, const u16* __restrict__ Wt1c,
    const float* __restrict__ sclG0, const float* __restrict__ sftG0,
    float* __restrict__ stOut)
{
  __shared__ u16 X0c[8*128*8];   // 16 KB
  __shared__ u16 W1c[8*128*8];   // 16 KB
  __shared__ float scl0[64], sft0[64];
  int tid = threadIdx.x;
  int m0 = blockIdx.x * 128;
  int b = m0 >> 15;

  if (tid < 64) { scl0[tid] = sclG0[tid]; sft0[tid] = sftG0[tid]; }
  for (int i = 0; i < 4; ++i)
    ((uint4*)W1c)[i*256 + tid] = ((const uint4*)Wt1c)[i*256 + tid];

  int pos = tid & 127, half = tid >> 7;
  {
    int m = m0 + pos;
    int nb = nidx[m];
    int p = (m & 32767) >> 5;
    int sp = sidx[b*NPP + p];
    const u16* urow = U + ((size_t)(b*NN + nb))*64 + half*32;
    const u16* trow = T + ((size_t)(b*NN + sp))*64 + half*32;
    u16 us[32], ts[32];
    for (int t = 0; t < 4; ++t) {
      *(uint4*)&us[t*8] = ((const uint4*)urow)[t];
      *(uint4*)&ts[t*8] = ((const uint4*)trow)[t];
    }
    __syncthreads();   // scl0 ready
    u16 ob[32];
    for (int j = 0; j < 32; ++j) {
      int c = half*32 + j;
      float d = bf2f(us[j]) - bf2f(ts[j]);
      ob[j] = f2bf(fmaxf(fmaf(scl0[c], d, sft0[c]), 0.f));
    }
    for (int t = 0; t < 4; ++t)
      *(uint4*)&X0c[((half*4+t)*128 + pos)*8] = *(uint4*)&ob[t*8];
  }
  __syncthreads();

  int lane = tid & 63, wv = tid >> 6, l31 = lane & 31, kh = lane >> 5;
  f32x16 acc[4];
  for (int mt = 0; mt < 4; ++mt) for (int r = 0; r < 16; ++r) acc[mt][r] = 0.f;

  for (int kt = 0; kt < 4; ++kt) {
    int ck = kt*2 + kh;
    short8 bfrag = *(const short8*)&W1c[(ck*128 + wv*32 + l31)*8];
    for (int mt = 0; mt < 4; ++mt) {
      short8 afrag = *(const short8*)&X0c[(ck*128 + mt*32 + l31)*8];
      acc[mt] = MFMA32(afrag, bfrag, acc[mt]);
    }
  }

  float s = 0.f, q = 0.f;
  for (int mt = 0; mt < 4; ++mt)
    for (int r = 0; r < 16; ++r) { float y = acc[mt][r]; s += y; q += y*y; }
  s += __shfl_xor(s, 32); q += __shfl_xor(q, 32);
  if (lane < 32) {
    int slot = (blockIdx.x*4 + wv) & 63;
    atomicAdd(&stOut[slot*256 + wv*32 + lane], s);
    atomicAdd(&stOut[SQOFF + slot*256 + wv*32 + lane], q);
  }
}

// ---------------------------------------------------------------------------
// L2 fused: gather U-T -> BN0+ReLU -> GEMM1 (A=W1,B=X0) -> BN1+ReLU -> b64
// scatter into padded X1c -> GEMM2 -> stats2 + max/min. M=64, grid 4096.
// ---------------------------------------------------------------------------
__global__ __launch_bounds__(256) void k_l2f(
    const int* __restrict__ sidx, const int* __restrict__ nidx,
    const u16* __restrict__ U, const u16* __restrict__ T,
    const u16* __restrict__ Wt1c, const u16* __restrict__ Wt2c,
    const float* __restrict__ sclG0, const float* __restrict__ sftG0,
    const float* __restrict__ sclG1, const float* __restrict__ sftG1,
    float* __restrict__ stOut, u16* __restrict__ mxp, u16* __restrict__ mnp)
{
  __shared__ u16 X1c[16*520];    // padded chunks (stride 520 u16)
  __shared__ u16 UB[16384];      // 32 KB: ph1 X0c[0,4096)+W1c[4096,12288); ph2 W2 half
  __shared__ float scl0[64], sft0[64], scl1[128], sft1[128];
  int tid = threadIdx.x;
  int m0 = blockIdx.x * 64;
  int b = m0 >> 15;

  if (tid < 64) { scl0[tid] = sclG0[tid]; sft0[tid] = sftG0[tid]; }
  if (tid < 128) { scl1[tid] = sclG1[tid]; sft1[tid] = sftG1[tid]; }
  u16* X0c = UB;          // [8 kc][64 m][8]
  u16* W1c = UB + 4096;   // [8 kc][128 n][8]
  for (int i = 0; i < 4; ++i)
    ((uint4*)W1c)[i*256 + tid] = ((const uint4*)Wt1c)[i*256 + tid];

  int pos = tid & 63, grp = tid >> 6;
  {
    int m = m0 + pos;
    int nb = nidx[m];
    int p = (m & 32767) >> 5;
    int sp = sidx[b*NPP + p];
    const u16* urow = U + ((size_t)(b*NN + nb))*64 + grp*16;
    const u16* trow = T + ((size_t)(b*NN + sp))*64 + grp*16;
    u16 us[16], ts[16];
    *(uint4*)&us[0] = ((const uint4*)urow)[0];
    *(uint4*)&us[8] = ((const uint4*)urow)[1];
    *(uint4*)&ts[0] = ((const uint4*)trow)[0];
    *(uint4*)&ts[8] = ((const uint4*)trow)[1];
    __syncthreads();   // scl0/scl1 ready, W1c staged
    u16 ob[16];
    for (int j = 0; j < 16; ++j) {
      int c = grp*16 + j;
      float d = bf2f(us[j]) - bf2f(ts[j]);
      ob[j] = f2bf(fmaxf(fmaf(scl0[c], d, sft0[c]), 0.f));
    }
    *(uint4*)&X0c[((2*grp)*64 + pos)*8]   = *(uint4*)&ob[0];
    *(uint4*)&X0c[((2*grp+1)*64 + pos)*8] = *(uint4*)&ob[8];
  }
  __syncthreads();

  int lane = tid & 63, wv = tid >> 6, l31 = lane & 31, kh = lane >> 5;

  // ---- GEMM1 swapped: A=W1 (rows=ch), B=X0 (cols=pos) ----
  f32x16 acc1[2];
  for (int nt = 0; nt < 2; ++nt) for (int r = 0; r < 16; ++r) acc1[nt][r] = 0.f;
  for (int kt = 0; kt < 4; ++kt) {
    int ck = kt*2 + kh;
    short8 afrag = *(const short8*)&W1c[(ck*128 + wv*32 + l31)*8];
    for (int nt = 0; nt < 2; ++nt) {
      short8 bfrag = *(const short8*)&X0c[(ck*64 + nt*32 + l31)*8];
      acc1[nt] = MFMA32(afrag, bfrag, acc1[nt]);
    }
  }
  __syncthreads();   // all UB (X0c/W1c) reads done

  // ---- BN1+ReLU + b64 scatter (4 consecutive channels per write) ----
  {
    float s1r[16], f1r[16];
    for (int r = 0; r < 16; ++r) {
      int ch = wv*32 + (r&3) + 8*(r>>2) + 4*kh;
      s1r[r] = scl1[ch]; f1r[r] = sft1[ch];
    }
    for (int nt = 0; nt < 2; ++nt) {
      int posn = nt*32 + l31;
      for (int g = 0; g < 4; ++g) {
        float v0 = fmaxf(fmaf(s1r[g*4+0], acc1[nt][g*4+0], f1r[g*4+0]), 0.f);
        float v1 = fmaxf(fmaf(s1r[g*4+1], acc1[nt][g*4+1], f1r[g*4+1]), 0.f);
        float v2 = fmaxf(fmaf(s1r[g*4+2], acc1[nt][g*4+2], f1r[g*4+2]), 0.f);
        float v3 = fmaxf(fmaf(s1r[g*4+3], acc1[nt][g*4+3], f1r[g*4+3]), 0.f);
        uint2 w = { pack2(v0, v1), pack2(v2, v3) };
        *(uint2*)&X1c[(wv*4 + g)*520 + posn*8 + 4*kh] = w;
      }
    }
  }
  __syncthreads();   // X1c complete before GEMM2 / UB overwrite

  // ---- GEMM2: A=X1 (rows=pos), B=W2 (cols=ch); W2 staged in 32KB halves ----
  f32x16 acc2[2][2];
  for (int nt = 0; nt < 2; ++nt) for (int mt = 0; mt < 2; ++mt)
    for (int r = 0; r < 16; ++r) acc2[nt][mt][r] = 0.f;

  for (int h = 0; h < 2; ++h) {
    for (int i = 0; i < 8; ++i)
      ((uint4*)UB)[i*256 + tid] = ((const uint4*)Wt2c)[h*2048 + i*256 + tid];
    __syncthreads();
    for (int k4 = 0; k4 < 4; ++k4) {
      int ckx = (h*4 + k4)*2 + kh;
      int ckw = k4*2 + kh;
      short8 a[2], bf_[2];
      for (int mt = 0; mt < 2; ++mt) a[mt]  = *(const short8*)&X1c[ckx*520 + (mt*32 + l31)*8];
      for (int nt = 0; nt < 2; ++nt) bf_[nt] = *(const short8*)&UB[(ckw*256 + wv*64 + nt*32 + l31)*8];
      for (int nt = 0; nt < 2; ++nt)
        for (int mt = 0; mt < 2; ++mt)
          acc2[nt][mt] = MFMA32(a[mt], bf_[nt], acc2[nt][mt]);
    }
    __syncthreads();
  }

  // ---- stats2 + max/min over NS (p-groups = row tiles mt) ----
  int slot = (blockIdx.x*4 + wv) & 63;
  for (int nt = 0; nt < 2; ++nt) {
    float s = 0.f, q = 0.f;
    float mx[2] = {-3.0e38f, -3.0e38f}, mn[2] = {3.0e38f, 3.0e38f};
    for (int mt = 0; mt < 2; ++mt)
      for (int r = 0; r < 16; ++r) {
        float y = acc2[nt][mt][r];
        s += y; q += y*y;
        mx[mt] = fmaxf(mx[mt], y); mn[mt] = fminf(mn[mt], y);
      }
    s += __shfl_xor(s, 32); q += __shfl_xor(q, 32);
    mx[0] = fmaxf(mx[0], __shfl_xor(mx[0], 32));
    mx[1] = fmaxf(mx[1], __shfl_xor(mx[1], 32));
    mn[0] = fminf(mn[0], __shfl_xor(mn[0], 32));
    mn[1] = fminf(mn[1], __shfl_xor(mn[1], 32));
    if (lane < 32) {
      int c = wv*64 + nt*32 + lane;
      atomicAdd(&stOut[slot*256 + c], s);
      atomicAdd(&stOut[SQOFF + slot*256 + c], q);
      for (int mt = 0; mt < 2; ++mt) {
        size_t pr = (size_t)blockIdx.x*2 + mt;
        mxp[pr*H2 + c] = f2bf(mx[mt]);
        mnp[pr*H2 + c] = f2bf(mn[mt]);
      }
    }
  }
}

// ---------------------------------------------------------------------------
__global__ __launch_bounds__(256) void k_final(
    const u16* __restrict__ mxp, const u16* __restrict__ mnp,
    const float* __restrict__ sclG2, const float* __restrict__ sftG2,
    float* __restrict__ out_np)
{
  __shared__ float tmp[256][33];
  int tid = threadIdx.x;
  int b = blockIdx.x >> 5;
  int p0 = (blockIdx.x & 31) * 32;

  float sc = sclG2[tid];
  float sh = sftG2[tid];

  for (int pp = 0; pp < 32; ++pp) {
    size_t base = ((size_t)(b*NPP + p0 + pp))*H2 + tid;
    float xv = bf2f(mxp[base]), nv = bf2f(mnp[base]);
    float v = (sc >= 0.f) ? fmaf(sc, xv, sh) : fmaf(sc, nv, sh);
    tmp[tid][pp] = fmaxf(v, 0.f);
  }
  __syncthreads();

  int pl = tid & 31, cg = tid >> 5;
  for (int cc = 0; cc < 32; ++cc) {
    int c = cc*8 + cg;
    out_np[((size_t)b*H2 + c)*NPP + p0 + pl] = tmp[c][pl];
  }
}

// ---------------------------------------------------------------------------
extern "C" void kernel_launch(void* const* d_in, const int* in_sizes, int n_in,
                              void* d_out, int out_size, void* d_ws, size_t ws_size,
                              hipStream_t stream)
{
  const float* xyz    = (const float*)d_in[0];
  const float* points = (const float*)d_in[1];
  const int*   sidx   = (const int*)d_in[2];
  const int*   nidx   = (const int*)d_in[3];
  const float* W0 = (const float*)d_in[4];
  const float* g0 = (const float*)d_in[6];
  const float* e0 = (const float*)d_in[7];
  const float* W1 = (const float*)d_in[8];
  const float* g1 = (const float*)d_in[10];
  const float* e1 = (const float*)d_in[11];
  const float* W2 = (const float*)d_in[12];
  const float* g2 = (const float*)d_in[14];
  const float* e2 = (const float*)d_in[15];

  float* out_xyz = (float*)d_out;
  float* out_np  = out_xyz + (size_t)BB*NPP*3;

  if (ws_size < (size_t)WS_NEED) {
    hipMemsetAsync(out_np, 0, (size_t)BB*H2*NPP*4, stream);
    k_xyz_only<<<32, 256, 0, stream>>>(xyz, sidx, out_xyz);
    return;
  }

  char* ws = (char*)d_ws;
  float* stats = (float*)(ws + 0);
  u16*   Wt0c  = (u16*)(ws + 393216);
  u16*   Wt1c  = (u16*)(ws + 403456);
  u16*   Wt2c  = (u16*)(ws + 419840);
  u16*   Ubuf  = (u16*)(ws + 485376);
  u16*   Tbuf  = (u16*)(ws + 4679680);
  u16*   mxp   = (u16*)(ws + 8873984);
  u16*   mnp   = (u16*)(ws + 13068288);
  float* bnc   = (float*)(ws + 17262592);
  float *scl0G = bnc,        *sft0G = bnc + 256;
  float *scl1G = bnc + 512,  *sft1G = bnc + 768;
  float *scl2G = bnc + 1024, *sft2G = bnc + 1280;

  hipMemsetAsync(stats, 0, 3*LSTRIDE*sizeof(float), stream);
  k_setup<<<42, 256, 0, stream>>>(xyz, sidx, W0, W1, W2, Wt0c, Wt1c, Wt2c, out_xyz);
  k_uv<<<NTOT/128, 256, 0, stream>>>(xyz, points, Wt0c, Ubuf, Tbuf);
  k_s0<<<MTOT/128, 256, 0, stream>>>(sidx, nidx, Ubuf, Tbuf, stats);
  k_fin<<<1, 256, 0, stream>>>(stats, g0, e0, 64, scl0G, sft0G);
  k_l1s<<<MTOT/128, 256, 0, stream>>>(sidx, nidx, Ubuf, Tbuf, Wt1c,
                                      scl0G, sft0G, stats + LSTRIDE);
  k_fin<<<1, 256, 0, stream>>>(stats + LSTRIDE, g1, e1, 128, scl1G, sft1G);
  k_l2f<<<MTOT/64, 256, 0, stream>>>(sidx, nidx, Ubuf, Tbuf, Wt1c, Wt2c,
                                     scl0G, sft0G, scl1G, sft1G,
                                     stats + 2*LSTRIDE, mxp, mnp);
  k_fin<<<1, 256, 0, stream>>>(stats + 2*LSTRIDE, g2, e2, 256, scl2G, sft2G);
  k_final<<<256, 256, 0, stream>>>(mxp, mnp, scl2G, sft2G, out_np);
}

// Round 10
// 207.587 us; speedup vs baseline: 1.2754x; 1.0290x over previous
//
#include <hip/hip_runtime.h>

typedef unsigned short u16;
typedef unsigned int u32;
typedef __attribute__((ext_vector_type(8))) short short8;    // 8 bf16
typedef __attribute__((ext_vector_type(16))) float f32x16;

#define BB 8
#define NN 4096
#define NPP 1024
#define NSS 32
#define CFF 64
#define C0 67
#define H0 64
#define H1 128
#define H2 256
#define NTOT (BB*NN)        // 32768 points
#define MTOT (BB*NPP*NSS)   // 262144
#define BN_EPS 1e-5f
#define INV_M (1.0f/262144.0f)
#define NSLOT 64
#define SQOFF 16384         // 64 slots * 256 ch
#define LSTRIDE 32768       // floats per layer (sum + sq)

#define MFMA32(a,b,c) __builtin_amdgcn_mfma_f32_32x32x16_bf16(a,b,c,0,0,0)

__device__ __forceinline__ float bf2f(u16 h){ return __uint_as_float(((u32)h)<<16); }
__device__ __forceinline__ u16 f2bf(float f){
  u32 u = __float_as_uint(f);
  u32 r = (u + 0x7fffu + ((u>>16)&1u)) >> 16;
  return (u16)r;
}
__device__ __forceinline__ u32 pack2(float a, float b){
  return (u32)f2bf(a) | ((u32)f2bf(b)<<16);
}

// ---------------------------------------------------------------------------
// R10 hybrid: k_uv per-point GEMM (U,T) -> k_s0y gathers ONCE (writes y0=U-T
// coalesced + stats0) -> l1s/l2f stream y0 coalesced (R6-style staging, R9
// fixes: sclG preload, padded scatter, 64-slot atomics).
//
// ws layout (bytes), total 42,434,560:
//   stats [0,393216)         3 layers x [64][256] sum + [64][256] sq f32
//   Wt0c  [393216,403456)    [10][64][8] bf16
//   Wt1c  [403456,419840)    [8][128][8]
//   Wt2c  [419840,485376)    [16][256][8]
//   bnc   [485376,491520)    6 x 256 f32
//   U     [491520,4685824)   (NTOT,64) bf16   -- dead after s0y; mxp aliases
//   T     [4685824,8880128)  (NTOT,64) bf16   -- dead after s0y; mnp aliases
//   y0    [8880128,42434560) (MTOT,64) bf16
// ---------------------------------------------------------------------------
#define WS_NEED 42434560u

__global__ __launch_bounds__(256) void k_setup(
    const float* __restrict__ xyz, const int* __restrict__ sidx,
    const float* __restrict__ W0, const float* __restrict__ W1, const float* __restrict__ W2,
    u16* __restrict__ Wt0c, u16* __restrict__ Wt1c, u16* __restrict__ Wt2c,
    float* __restrict__ out_newxyz)
{
  int blk = blockIdx.x, tid = threadIdx.x;
  if (blk < 32) {
    int t0 = blk*256 + tid;                  // b*NP + p
    int b = t0 >> 10;
    int s = sidx[t0];
    for (int k = 0; k < 3; ++k)
      out_newxyz[(size_t)t0*3 + k] = xyz[((size_t)(b*NN + s))*3 + k];
  } else if (blk == 32) {
    for (int i = 0; i < 20; ++i) {
      int e = i*256 + tid;                   // [10 kc][64 o][8 j]
      if (e >= 5120) break;
      int kc = e >> 9, o = (e >> 3) & 63, j = e & 7;
      float v;
      if (kc < 8)       v = W0[o*C0 + 3 + kc*8 + j];
      else if (kc == 8) v = (j < 3) ? W0[o*C0 + j] : 0.f;
      else              v = 0.f;
      Wt0c[e] = f2bf(v);
    }
  } else if (blk == 33) {
    for (int i = 0; i < 32; ++i) {
      int e = i*256 + tid;                   // [8 kc][128 n][8 j]
      int kc = e >> 10, n = (e >> 3) & 127, j = e & 7;
      Wt1c[e] = f2bf(W1[n*H0 + kc*8 + j]);
    }
  } else {
    int base = (blk - 34) * 4096;            // blocks 34..41
    for (int i = 0; i < 16; ++i) {
      int e = base + i*256 + tid;            // [16 kc][256 n][8 j]
      int kc = e >> 11, n = (e >> 3) & 255, j = e & 7;
      Wt2c[e] = f2bf(W2[n*H1 + kc*8 + j]);
    }
  }
}

__global__ __launch_bounds__(256) void k_xyz_only(
    const float* __restrict__ xyz, const int* __restrict__ sidx, float* __restrict__ out_newxyz)
{
  int t0 = blockIdx.x*256 + threadIdx.x;
  int b = t0 >> 10;
  int s = sidx[t0];
  for (int k = 0; k < 3; ++k)
    out_newxyz[(size_t)t0*3 + k] = xyz[((size_t)(b*NN + s))*3 + k];
}

// ---------------------------------------------------------------------------
// fin: reduce 64 stat slots -> scl/sft (grid = 1 block)
// ---------------------------------------------------------------------------
__global__ __launch_bounds__(256) void k_fin(
    const float* __restrict__ stIn, const float* __restrict__ gma,
    const float* __restrict__ bta, int nch,
    float* __restrict__ sclG, float* __restrict__ sftG)
{
  int c = threadIdx.x;
  if (c < nch) {
    float s = 0.f, q = 0.f;
    for (int sl = 0; sl < NSLOT; ++sl) { s += stIn[sl*256 + c]; q += stIn[SQOFF + sl*256 + c]; }
    float mu = s*INV_M, var = q*INV_M - mu*mu;
    float sc = gma[c] * rsqrtf(var + BN_EPS);
    sclG[c] = sc; sftG[c] = bta[c] - mu*sc;
  }
}

// ---------------------------------------------------------------------------
// UV: per-point GEMM. M=128 points/block, grid 256. K=80 (10 chunks):
// accT from chunks 8,9 (xyz), accU = accT + chunks 0..7 (feat).
// ---------------------------------------------------------------------------
__global__ __launch_bounds__(256) void k_uv(
    const float* __restrict__ xyz, const float* __restrict__ points,
    const u16* __restrict__ Wt0c, u16* __restrict__ U, u16* __restrict__ T)
{
  __shared__ u16 XLc[10*128*8];  // 20 KB
  __shared__ u16 W0c[10*64*8];   // 10 KB
  int tid = threadIdx.x;
  int gn0 = blockIdx.x * 128;
  int b = gn0 >> 12;
  int n0 = gn0 & 4095;

  for (int i = 0; i < 3; ++i) {
    int e = i*256 + tid;
    if (e < 640) ((uint4*)W0c)[e] = ((const uint4*)Wt0c)[e];
  }
  {
    int c = tid >> 2, nseg = tid & 3;        // 64 ch x 4 n-segments
    const float* src = points + ((size_t)(b*CFF + c))*NN + n0 + nseg*32;
    int cb = c >> 3, cr = c & 7;
    for (int t = 0; t < 8; ++t) {
      float4 v = *(const float4*)(src + t*4);
      int n = nseg*32 + t*4;
      XLc[(cb*128 + n+0)*8 + cr] = f2bf(v.x);
      XLc[(cb*128 + n+1)*8 + cr] = f2bf(v.y);
      XLc[(cb*128 + n+2)*8 + cr] = f2bf(v.z);
      XLc[(cb*128 + n+3)*8 + cr] = f2bf(v.w);
    }
  }
  if (tid < 128) {
    int gn = gn0 + tid;
    float x = xyz[(size_t)gn*3+0], y = xyz[(size_t)gn*3+1], z = xyz[(size_t)gn*3+2];
    uint4 v = { pack2(x,y), pack2(z,0.f), 0u, 0u };
    *(uint4*)&XLc[(8*128 + tid)*8] = v;
  } else {
    uint4 z4 = {0u,0u,0u,0u};
    *(uint4*)&XLc[(9*128 + (tid-128))*8] = z4;
  }
  __syncthreads();

  int lane = tid & 63, wv = tid >> 6, l31 = lane & 31, kh = lane >> 5;
  int nt = wv & 1, mtb = (wv >> 1)*2;
  f32x16 accT2[2], accU2[2];
  for (int mi = 0; mi < 2; ++mi) for (int r = 0; r < 16; ++r) accT2[mi][r] = 0.f;

  {
    int ck = 8 + kh;
    short8 bfrag = *(const short8*)&W0c[(ck*64 + nt*32 + l31)*8];
    for (int mi = 0; mi < 2; ++mi) {
      short8 afrag = *(const short8*)&XLc[(ck*128 + (mtb+mi)*32 + l31)*8];
      accT2[mi] = MFMA32(afrag, bfrag, accT2[mi]);
    }
  }
  for (int mi = 0; mi < 2; ++mi) accU2[mi] = accT2[mi];
  for (int kt = 0; kt < 4; ++kt) {
    int ck = kt*2 + kh;
    short8 bfrag = *(const short8*)&W0c[(ck*64 + nt*32 + l31)*8];
    for (int mi = 0; mi < 2; ++mi) {
      short8 afrag = *(const short8*)&XLc[(ck*128 + (mtb+mi)*32 + l31)*8];
      accU2[mi] = MFMA32(afrag, bfrag, accU2[mi]);
    }
  }

  int c = nt*32 + l31;
  for (int mi = 0; mi < 2; ++mi)
    for (int r = 0; r < 16; ++r) {
      int gm = gn0 + (mtb+mi)*32 + (r&3) + 8*(r>>2) + 4*kh;
      U[(size_t)gm*64 + c] = f2bf(accU2[mi][r]);
      T[(size_t)gm*64 + c] = f2bf(accT2[mi][r]);
    }
}

// ---------------------------------------------------------------------------
// s0y: THE gather pass. d = U[nb]-T[sp] -> y0 bf16 (coalesced) + stats0.
// Grid 2048, 128 m/block. thread: 8 ch (c0=(tid&7)*8), 4 m (rg=tid>>3).
// ---------------------------------------------------------------------------
__global__ __launch_bounds__(256) void k_s0y(
    const int* __restrict__ sidx, const int* __restrict__ nidx,
    const u16* __restrict__ U, const u16* __restrict__ T,
    u16* __restrict__ y0, float* __restrict__ stats)
{
  int tid = threadIdx.x;
  int m0 = blockIdx.x * 128;
  int b = m0 >> 15;
  int c0 = (tid & 7) * 8;
  int rg = tid >> 3;
  int wv = tid >> 6;
  int mbase = m0 + rg*4;
  int p = (mbase & 32767) >> 5;
  int sp = sidx[b*NPP + p];
  u16 tv[8];
  *(uint4*)tv = *(const uint4*)(T + ((size_t)(b*NN + sp))*64 + c0);
  float tf[8], s[8], q[8];
  for (int j = 0; j < 8; ++j) { tf[j] = bf2f(tv[j]); s[j] = 0.f; q[j] = 0.f; }
  int nb[4];
  for (int i = 0; i < 4; ++i) nb[i] = nidx[mbase + i];
  for (int i = 0; i < 4; ++i) {
    u16 uv[8], ov[8];
    *(uint4*)uv = *(const uint4*)(U + ((size_t)(b*NN + nb[i]))*64 + c0);
    for (int j = 0; j < 8; ++j) {
      float d = bf2f(uv[j]) - tf[j];
      s[j] += d; q[j] += d*d;
      ov[j] = f2bf(d);
    }
    *(uint4*)(y0 + ((size_t)(mbase + i))*64 + c0) = *(uint4*)ov;
  }
  for (int msk = 8; msk <= 32; msk <<= 1)
    for (int j = 0; j < 8; ++j) {
      s[j] += __shfl_xor(s[j], msk);
      q[j] += __shfl_xor(q[j], msk);
    }
  if ((tid & 63) < 8) {
    int slot = (blockIdx.x*4 + wv) & 63;
    for (int j = 0; j < 8; ++j) {
      atomicAdd(&stats[slot*256 + c0 + j], s[j]);
      atomicAdd(&stats[SQOFF + slot*256 + c0 + j], q[j]);
    }
  }
}

// ---------------------------------------------------------------------------
// L1 stats: stream y0, BN0+ReLU -> X0c, GEMM1 -> stats1. M=128, grid 2048.
// ---------------------------------------------------------------------------
__global__ __launch_bounds__(256) void k_l1s(
    const u16* __restrict__ y0, const u16* __restrict__ Wt1c,
    const float* __restrict__ sclG0, const float* __restrict__ sftG0,
    float* __restrict__ stOut)
{
  __shared__ u16 X0c[8*128*8];   // 16 KB
  __shared__ u16 W1c[8*128*8];   // 16 KB
  __shared__ float scl0[64], sft0[64];
  int tid = threadIdx.x;
  int m0 = blockIdx.x * 128;

  if (tid < 64) { scl0[tid] = sclG0[tid]; sft0[tid] = sftG0[tid]; }
  for (int i = 0; i < 4; ++i)
    ((uint4*)W1c)[i*256 + tid] = ((const uint4*)Wt1c)[i*256 + tid];

  int pos = tid & 127, half = tid >> 7;
  {
    const u16* row = y0 + (size_t)(m0 + pos)*64 + half*32;
    u16 hs[32];
    for (int t = 0; t < 4; ++t) *(uint4*)&hs[t*8] = ((const uint4*)row)[t];
    __syncthreads();   // scl0 ready
    u16 ob[32];
    for (int j = 0; j < 32; ++j) {
      int c = half*32 + j;
      ob[j] = f2bf(fmaxf(fmaf(scl0[c], bf2f(hs[j]), sft0[c]), 0.f));
    }
    for (int t = 0; t < 4; ++t)
      *(uint4*)&X0c[((half*4+t)*128 + pos)*8] = *(uint4*)&ob[t*8];
  }
  __syncthreads();

  int lane = tid & 63, wv = tid >> 6, l31 = lane & 31, kh = lane >> 5;
  f32x16 acc[4];
  for (int mt = 0; mt < 4; ++mt) for (int r = 0; r < 16; ++r) acc[mt][r] = 0.f;

  for (int kt = 0; kt < 4; ++kt) {
    int ck = kt*2 + kh;
    short8 bfrag = *(const short8*)&W1c[(ck*128 + wv*32 + l31)*8];
    for (int mt = 0; mt < 4; ++mt) {
      short8 afrag = *(const short8*)&X0c[(ck*128 + mt*32 + l31)*8];
      acc[mt] = MFMA32(afrag, bfrag, acc[mt]);
    }
  }

  float s = 0.f, q = 0.f;
  for (int mt = 0; mt < 4; ++mt)
    for (int r = 0; r < 16; ++r) { float y = acc[mt][r]; s += y; q += y*y; }
  s += __shfl_xor(s, 32); q += __shfl_xor(q, 32);
  if (lane < 32) {
    int slot = (blockIdx.x*4 + wv) & 63;
    atomicAdd(&stOut[slot*256 + wv*32 + lane], s);
    atomicAdd(&stOut[SQOFF + slot*256 + wv*32 + lane], q);
  }
}

// ---------------------------------------------------------------------------
// L2 fused: stream y0 -> BN0+ReLU -> GEMM1 (A=W1,B=X0) -> BN1+ReLU -> b64
// scatter into padded X1c -> GEMM2 -> stats2 + max/min. M=64, grid 4096.
// ---------------------------------------------------------------------------
__global__ __launch_bounds__(256) void k_l2f(
    const u16* __restrict__ y0,
    const u16* __restrict__ Wt1c, const u16* __restrict__ Wt2c,
    const float* __restrict__ sclG0, const float* __restrict__ sftG0,
    const float* __restrict__ sclG1, const float* __restrict__ sftG1,
    float* __restrict__ stOut, u16* __restrict__ mxp, u16* __restrict__ mnp)
{
  __shared__ u16 X1c[16*520];    // padded chunks (stride 520 u16)
  __shared__ u16 UB[16384];      // 32 KB: ph1 X0c[0,4096)+W1c[4096,12288); ph2 W2 half
  __shared__ float scl0[64], sft0[64], scl1[128], sft1[128];
  int tid = threadIdx.x;
  int m0 = blockIdx.x * 64;

  if (tid < 64) { scl0[tid] = sclG0[tid]; sft0[tid] = sftG0[tid]; }
  if (tid < 128) { scl1[tid] = sclG1[tid]; sft1[tid] = sftG1[tid]; }
  u16* X0c = UB;          // [8 kc][64 m][8]
  u16* W1c = UB + 4096;   // [8 kc][128 n][8]
  for (int i = 0; i < 4; ++i)
    ((uint4*)W1c)[i*256 + tid] = ((const uint4*)Wt1c)[i*256 + tid];

  int pos = tid & 63, grp = tid >> 6;
  {
    const u16* row = y0 + (size_t)(m0 + pos)*64 + grp*16;
    u16 hs[16];
    *(uint4*)&hs[0] = ((const uint4*)row)[0];
    *(uint4*)&hs[8] = ((const uint4*)row)[1];
    __syncthreads();   // scl0/scl1 ready, W1c staged
    u16 ob[16];
    for (int j = 0; j < 16; ++j) {
      int c = grp*16 + j;
      ob[j] = f2bf(fmaxf(fmaf(scl0[c], bf2f(hs[j]), sft0[c]), 0.f));
    }
    *(uint4*)&X0c[((2*grp)*64 + pos)*8]   = *(uint4*)&ob[0];
    *(uint4*)&X0c[((2*grp+1)*64 + pos)*8] = *(uint4*)&ob[8];
  }
  __syncthreads();

  int lane = tid & 63, wv = tid >> 6, l31 = lane & 31, kh = lane >> 5;

  // ---- GEMM1 swapped: A=W1 (rows=ch), B=X0 (cols=pos) ----
  f32x16 acc1[2];
  for (int nt = 0; nt < 2; ++nt) for (int r = 0; r < 16; ++r) acc1[nt][r] = 0.f;
  for (int kt = 0; kt < 4; ++kt) {
    int ck = kt*2 + kh;
    short8 afrag = *(const short8*)&W1c[(ck*128 + wv*32 + l31)*8];
    for (int nt = 0; nt < 2; ++nt) {
      short8 bfrag = *(const short8*)&X0c[(ck*64 + nt*32 + l31)*8];
      acc1[nt] = MFMA32(afrag, bfrag, acc1[nt]);
    }
  }
  __syncthreads();   // all UB (X0c/W1c) reads done

  // ---- BN1+ReLU + b64 scatter (4 consecutive channels per write) ----
  {
    float s1r[16], f1r[16];
    for (int r = 0; r < 16; ++r) {
      int ch = wv*32 + (r&3) + 8*(r>>2) + 4*kh;
      s1r[r] = scl1[ch]; f1r[r] = sft1[ch];
    }
    for (int nt = 0; nt < 2; ++nt) {
      int posn = nt*32 + l31;
      for (int g = 0; g < 4; ++g) {
        float v0 = fmaxf(fmaf(s1r[g*4+0], acc1[nt][g*4+0], f1r[g*4+0]), 0.f);
        float v1 = fmaxf(fmaf(s1r[g*4+1], acc1[nt][g*4+1], f1r[g*4+1]), 0.f);
        float v2 = fmaxf(fmaf(s1r[g*4+2], acc1[nt][g*4+2], f1r[g*4+2]), 0.f);
        float v3 = fmaxf(fmaf(s1r[g*4+3], acc1[nt][g*4+3], f1r[g*4+3]), 0.f);
        uint2 w = { pack2(v0, v1), pack2(v2, v3) };
        *(uint2*)&X1c[(wv*4 + g)*520 + posn*8 + 4*kh] = w;
      }
    }
  }
  __syncthreads();   // X1c complete before GEMM2 / UB overwrite

  // ---- GEMM2: A=X1 (rows=pos), B=W2 (cols=ch); W2 staged in 32KB halves ----
  f32x16 acc2[2][2];
  for (int nt = 0; nt < 2; ++nt) for (int mt = 0; mt < 2; ++mt)
    for (int r = 0; r < 16; ++r) acc2[nt][mt][r] = 0.f;

  for (int h = 0; h < 2; ++h) {
    for (int i = 0; i < 8; ++i)
      ((uint4*)UB)[i*256 + tid] = ((const uint4*)Wt2c)[h*2048 + i*256 + tid];
    __syncthreads();
    for (int k4 = 0; k4 < 4; ++k4) {
      int ckx = (h*4 + k4)*2 + kh;
      int ckw = k4*2 + kh;
      short8 a[2], bf_[2];
      for (int mt = 0; mt < 2; ++mt) a[mt]  = *(const short8*)&X1c[ckx*520 + (mt*32 + l31)*8];
      for (int nt = 0; nt < 2; ++nt) bf_[nt] = *(const short8*)&UB[(ckw*256 + wv*64 + nt*32 + l31)*8];
      for (int nt = 0; nt < 2; ++nt)
        for (int mt = 0; mt < 2; ++mt)
          acc2[nt][mt] = MFMA32(a[mt], bf_[nt], acc2[nt][mt]);
    }
    __syncthreads();
  }

  // ---- stats2 + max/min over NS (p-groups = row tiles mt) ----
  int slot = (blockIdx.x*4 + wv) & 63;
  for (int nt = 0; nt < 2; ++nt) {
    float s = 0.f, q = 0.f;
    float mx[2] = {-3.0e38f, -3.0e38f}, mn[2] = {3.0e38f, 3.0e38f};
    for (int mt = 0; mt < 2; ++mt)
      for (int r = 0; r < 16; ++r) {
        float y = acc2[nt][mt][r];
        s += y; q += y*y;
        mx[mt] = fmaxf(mx[mt], y); mn[mt] = fminf(mn[mt], y);
      }
    s += __shfl_xor(s, 32); q += __shfl_xor(q, 32);
    mx[0] = fmaxf(mx[0], __shfl_xor(mx[0], 32));
    mx[1] = fmaxf(mx[1], __shfl_xor(mx[1], 32));
    mn[0] = fminf(mn[0], __shfl_xor(mn[0], 32));
    mn[1] = fminf(mn[1], __shfl_xor(mn[1], 32));
    if (lane < 32) {
      int c = wv*64 + nt*32 + lane;
      atomicAdd(&stOut[slot*256 + c], s);
      atomicAdd(&stOut[SQOFF + slot*256 + c], q);
      for (int mt = 0; mt < 2; ++mt) {
        size_t pr = (size_t)blockIdx.x*2 + mt;
        mxp[pr*H2 + c] = f2bf(mx[mt]);
        mnp[pr*H2 + c] = f2bf(mn[mt]);
      }
    }
  }
}

// ---------------------------------------------------------------------------
__global__ __launch_bounds__(256) void k_final(
    const u16* __restrict__ mxp, const u16* __restrict__ mnp,
    const float* __restrict__ sclG2, const float* __restrict__ sftG2,
    float* __restrict__ out_np)
{
  __shared__ float tmp[256][33];
  int tid = threadIdx.x;
  int b = blockIdx.x >> 5;
  int p0 = (blockIdx.x & 31) * 32;

  float sc = sclG2[tid];
  float sh = sftG2[tid];

  for (int pp = 0; pp < 32; ++pp) {
    size_t base = ((size_t)(b*NPP + p0 + pp))*H2 + tid;
    float xv = bf2f(mxp[base]), nv = bf2f(mnp[base]);
    float v = (sc >= 0.f) ? fmaf(sc, xv, sh) : fmaf(sc, nv, sh);
    tmp[tid][pp] = fmaxf(v, 0.f);
  }
  __syncthreads();

  int pl = tid & 31, cg = tid >> 5;
  for (int cc = 0; cc < 32; ++cc) {
    int c = cc*8 + cg;
    out_np[((size_t)b*H2 + c)*NPP + p0 + pl] = tmp[c][pl];
  }
}

// ---------------------------------------------------------------------------
extern "C" void kernel_launch(void* const* d_in, const int* in_sizes, int n_in,
                              void* d_out, int out_size, void* d_ws, size_t ws_size,
                              hipStream_t stream)
{
  const float* xyz    = (const float*)d_in[0];
  const float* points = (const float*)d_in[1];
  const int*   sidx   = (const int*)d_in[2];
  const int*   nidx   = (const int*)d_in[3];
  const float* W0 = (const float*)d_in[4];
  const float* g0 = (const float*)d_in[6];
  const float* e0 = (const float*)d_in[7];
  const float* W1 = (const float*)d_in[8];
  const float* g1 = (const float*)d_in[10];
  const float* e1 = (const float*)d_in[11];
  const float* W2 = (const float*)d_in[12];
  const float* g2 = (const float*)d_in[14];
  const float* e2 = (const float*)d_in[15];

  float* out_xyz = (float*)d_out;
  float* out_np  = out_xyz + (size_t)BB*NPP*3;

  if (ws_size < (size_t)WS_NEED) {
    hipMemsetAsync(out_np, 0, (size_t)BB*H2*NPP*4, stream);
    k_xyz_only<<<32, 256, 0, stream>>>(xyz, sidx, out_xyz);
    return;
  }

  char* ws = (char*)d_ws;
  float* stats = (float*)(ws + 0);
  u16*   Wt0c  = (u16*)(ws + 393216);
  u16*   Wt1c  = (u16*)(ws + 403456);
  u16*   Wt2c  = (u16*)(ws + 419840);
  float* bnc   = (float*)(ws + 485376);
  u16*   Ubuf  = (u16*)(ws + 491520);
  u16*   Tbuf  = (u16*)(ws + 4685824);
  u16*   y0    = (u16*)(ws + 8880128);
  u16*   mxp   = Ubuf;   // aliases U (dead after k_s0y)
  u16*   mnp   = Tbuf;   // aliases T
  float *scl0G = bnc,        *sft0G = bnc + 256;
  float *scl1G = bnc + 512,  *sft1G = bnc + 768;
  float *scl2G = bnc + 1024, *sft2G = bnc + 1280;

  hipMemsetAsync(stats, 0, 3*LSTRIDE*sizeof(float), stream);
  k_setup<<<42, 256, 0, stream>>>(xyz, sidx, W0, W1, W2, Wt0c, Wt1c, Wt2c, out_xyz);
  k_uv<<<NTOT/128, 256, 0, stream>>>(xyz, points, Wt0c, Ubuf, Tbuf);
  k_s0y<<<MTOT/128, 256, 0, stream>>>(sidx, nidx, Ubuf, Tbuf, y0, stats);
  k_fin<<<1, 256, 0, stream>>>(stats, g0, e0, 64, scl0G, sft0G);
  k_l1s<<<MTOT/128, 256, 0, stream>>>(y0, Wt1c, scl0G, sft0G, stats + LSTRIDE);
  k_fin<<<1, 256, 0, stream>>>(stats + LSTRIDE, g1, e1, 128, scl1G, sft1G);
  k_l2f<<<MTOT/64, 256, 0, stream>>>(y0, Wt1c, Wt2c,
                                     scl0G, sft0G, scl1G, sft1G,
                                     stats + 2*LSTRIDE, mxp, mnp);
  k_fin<<<1, 256, 0, stream>>>(stats + 2*LSTRIDE, g2, e2, 256, scl2G, sft2G);
  k_final<<<256, 256, 0, stream>>>(mxp, mnp, scl2G, sft2G, out_np);
}